// Round 12
// baseline (809.941 us; speedup 1.0000x reference)
//
#include <hip/hip_runtime.h>
#include <hip/hip_bf16.h>

#define NN 32768   // nodes
#define NB 256     // graphs
#define HD 128     // hidden
#define NL 4       // layers
#define NE 262144  // edges

typedef short bf16x8 __attribute__((ext_vector_type(8)));
typedef float f32x4 __attribute__((ext_vector_type(4)));
typedef unsigned short u16;
typedef unsigned int u32;

__device__ __forceinline__ float bf2f(u16 u) {
  return __uint_as_float(((u32)u) << 16);
}
__device__ __forceinline__ u16 f2bf(float f) {
  u32 x = __float_as_uint(f);
  u32 r = x + 0x7FFFu + ((x >> 16) & 1u);
  return (u16)(r >> 16);
}
// packed f32x2 -> bf16x2 via compiler cvt_pk (RNE)
__device__ __forceinline__ u32 pk2(float a, float b) {
  __hip_bfloat162 h = __float22bfloat162_rn(make_float2(a, b));
  return *reinterpret_cast<u32*>(&h);
}
__device__ __forceinline__ float siluf(float x) {
  return x * __builtin_amdgcn_rcpf(1.0f + __expf(-x));
}
__device__ __forceinline__ float sigf(float x) {
  return __builtin_amdgcn_rcpf(1.0f + __expf(-x));
}
__device__ __forceinline__ u32 ordu(float f) {
  u32 b = __float_as_uint(f);
  return (b & 0x80000000u) ? ~b : (b | 0x80000000u);
}

// ---- adaptive input loads: mode 1 = f32 inputs, mode 0 = bf16 inputs ----
__device__ __forceinline__ float ldinf(const void* p, size_t i, int mode) {
  return mode ? ((const float*)p)[i] : bf2f(((const u16*)p)[i]);
}
__device__ __forceinline__ u16 ldinb(const void* p, size_t i, int mode) {
  return mode ? f2bf(((const float*)p)[i]) : ((const u16*)p)[i];
}

// ---- dtype detector (confirmed mode=1/f32; kept as cheap guard) ----
__global__ void k_detect(const u16* __restrict__ Weraw, int* __restrict__ flag) {
  if (threadIdx.x == 0 && blockIdx.x == 0) {
    int cnt = 0;
    for (int i = 0; i < 256; i++) {
      u16 u = Weraw[2 * i];
      u32 e = (u >> 7) & 0xFFu;
      if (e >= 112u && e <= 126u) cnt++;
    }
    *flag = (cnt >= 128) ? 0 : 1;
  }
}

// ================= SLOT ORDER =================
// All 128-wide feature rows (e, feat, msum, sacc/mxacc) are in "slot order":
// position s holds feature h = (s&7)*16 + (s>>3) — wave_pack's natural output.
// Weight panels fold the permutation: klog = ((s&7)<<4)|(s>>3).
// Lane l's GEMM output for row R, cols {nt*16+c} == slots {8c..8c+7} == int4
// granule c of the row  =>  epilogue RMWs are direct int4 ops, no shuffles.
// ================= SORTED EDGES =================
// Edge arrays (e rows, src_s, dst_s) are dst-sorted (CSR order); k_edge
// aggregates msum per dst-run in registers, one atomicAdd pair per run.

// ---------------- CSR build (by dst) ----------------
__global__ __launch_bounds__(256) void k_csr_deg(const int* __restrict__ dstp,
                                                 u32* __restrict__ deg) {
  const int i = blockIdx.x * 256 + threadIdx.x;
  atomicAdd(&deg[dstp[i]], 1u);
}

__global__ __launch_bounds__(1024) void k_csr_scan(const u32* __restrict__ deg,
                                                   int* __restrict__ rowptr,
                                                   int* __restrict__ cursor) {
  __shared__ int part[1024];
  const int t = threadIdx.x;
  int loc[32];
  int s = 0;
#pragma unroll
  for (int j = 0; j < 32; j++) { loc[j] = s; s += (int)deg[t * 32 + j]; }
  part[t] = s;
  __syncthreads();
  int inc = s;
  for (int off = 1; off < 1024; off <<= 1) {
    int tmp = (t >= off) ? part[t - off] : 0;
    __syncthreads();
    part[t] += tmp;
    __syncthreads();
  }
  const int base = part[t] - inc;
#pragma unroll
  for (int j = 0; j < 32; j++) {
    rowptr[t * 32 + j] = base + loc[j];
    cursor[t * 32 + j] = base + loc[j];
  }
  if (t == 1023) rowptr[NN] = part[1023];
}

__global__ __launch_bounds__(256) void k_csr_scatter(const int* __restrict__ dstp,
                                                     const int* __restrict__ srcp,
                                                     int* __restrict__ cursor,
                                                     int* __restrict__ eids,
                                                     int* __restrict__ src_s,
                                                     int* __restrict__ dst_s) {
  const int i = blockIdx.x * 256 + threadIdx.x;
  const int d = dstp[i];
  const int pos = atomicAdd(&cursor[d], 1);
  eids[pos] = i;
  src_s[pos] = srcp[i];
  dst_s[pos] = d;
}

// ---------------- per-wave GEMM pieces ----------------
// Wave tile: MT*16 rows x 128 cols, mfma_f32_16x16x32_bf16.
// A-frag: lane l holds A[row=(l&15)+16*mt][slot=(l>>4)*8+j]  (16B contiguous)
// B PACKED: Bp[((nt*4+ks)*64 + lane)*8 + j] = W[perm(slot)][col=nt*16+(lane&15)]
//   => every b-load is one CONTIGUOUS 1KB segment across the wave.
// C/D: col = lane&15, row = (lane>>4)*4 + reg  (m89-verified)
// LDS tile: [rows][128 shorts], XOR-swizzled 16B granules (g ^= row&7).
#define PANEL 16384  // shorts per packed 128x128 weight panel

template <int MT>
__device__ __forceinline__ void acc_zero(f32x4 (&acc)[MT][8]) {
#pragma unroll
  for (int mt = 0; mt < MT; mt++)
#pragma unroll
    for (int nt = 0; nt < 8; nt++) acc[mt][nt] = f32x4{0.f, 0.f, 0.f, 0.f};
}

template <int MT>
__device__ __forceinline__ void gemm_gp(const u16* __restrict__ A0,
                                        const size_t* rowoff,
                                        const u16* __restrict__ Bp,
                                        int l, int kg, f32x4 (&acc)[MT][8]) {
#pragma unroll
  for (int ks = 0; ks < 4; ks++) {
    bf16x8 a[MT];
#pragma unroll
    for (int mt = 0; mt < MT; mt++)
      a[mt] = *(const bf16x8*)&A0[rowoff[mt] + ks * 32 + kg * 8];
#pragma unroll
    for (int nt = 0; nt < 8; nt++) {
      bf16x8 b = *(const bf16x8*)&Bp[(size_t)((nt * 4 + ks) * 64 + l) * 8];
#pragma unroll
      for (int mt = 0; mt < MT; mt++)
        acc[mt][nt] = __builtin_amdgcn_mfma_f32_16x16x32_bf16(a[mt], b, acc[mt][nt], 0, 0, 0);
    }
  }
}

template <int MT>
__device__ __forceinline__ void wave_gemm_p(const short* lAw, const u16* __restrict__ Bp,
                                            int l, int c, int kg, f32x4 (&acc)[MT][8]) {
#pragma unroll
  for (int ks = 0; ks < 4; ks++) {
    bf16x8 a[MT];
#pragma unroll
    for (int mt = 0; mt < MT; mt++) {
      const int r = mt * 16 + c;
      const int k = ks * 32 + kg * 8;
      a[mt] = *(const bf16x8*)&lAw[r * HD + (k ^ ((r & 7) << 3))];
    }
#pragma unroll
    for (int nt = 0; nt < 8; nt++) {
      bf16x8 b = *(const bf16x8*)&Bp[(size_t)((nt * 4 + ks) * 64 + l) * 8];
#pragma unroll
      for (int mt = 0; mt < MT; mt++)
        acc[mt][nt] = __builtin_amdgcn_mfma_f32_16x16x32_bf16(a[mt], b, acc[mt][nt], 0, 0, 0);
    }
  }
}

template <int MT, bool SILU>
__device__ __forceinline__ void wave_pack(short* lAw, int c, int kg,
                                          f32x4 (&acc)[MT][8], const float* bias) {
#pragma unroll
  for (int mt = 0; mt < MT; mt++) {
#pragma unroll
    for (int rr = 0; rr < 4; rr++) {
      const int row = mt * 16 + kg * 4 + rr;
      u32 ou[4];
#pragma unroll
      for (int p = 0; p < 4; p++) {
        float x0 = acc[mt][2 * p][rr] + bias[2 * p];
        float x1 = acc[mt][2 * p + 1][rr] + bias[2 * p + 1];
        if (SILU) { x0 = siluf(x0); x1 = siluf(x1); }
        ou[p] = pk2(x0, x1);
      }
      ((int4*)(lAw + row * HD))[c ^ (row & 7)] =
          make_int4((int)ou[0], (int)ou[1], (int)ou[2], (int)ou[3]);
    }
  }
}

// ---------------- weight prep: pack panels, fold slot permutation -------------
__global__ __launch_bounds__(256) void k_prep(
    const void* __restrict__ mW1, const void* __restrict__ mW2,
    const void* __restrict__ uW1, const void* __restrict__ uW2,
    const void* __restrict__ oW1, const void* __restrict__ oW2,
    const int* __restrict__ flagp,
    u16* __restrict__ Wt1, u16* __restrict__ Wt2p,
    u16* __restrict__ Wtu1, u16* __restrict__ Wtu2p,
    u16* __restrict__ Wto1, u16* __restrict__ Wto2p) {
  const int mode = *flagp;
  const int tid = blockIdx.x * blockDim.x + threadIdx.x;
  const int stride = gridDim.x * blockDim.x;
  for (int i = tid; i < NL * 3 * PANEL; i += stride) {
    const int l = i / (3 * PANEL), r = i % (3 * PANEL);
    const int chunk = r / PANEL, r2 = r % PANEL;
    const int nt = r2 / 2048, ks = (r2 % 2048) / 512;
    const int lane = (r2 % 512) / 8, j = r2 % 8;
    const int s = ks * 32 + (lane >> 4) * 8 + j;
    const int klog = ((s & 7) << 4) | (s >> 3);
    const int n = nt * 16 + (lane & 15);
    Wt1[i] = ldinb(mW1, ((size_t)l * 384 + chunk * 128 + klog) * HD + n, mode);
  }
  for (int i = tid; i < NL * PANEL; i += stride) {
    const int l = i / PANEL, r = i % PANEL;
    const int nt = r / 2048, ks = (r % 2048) / 512;
    const int lane = (r % 512) / 8, j = r % 8;
    const int s = ks * 32 + (lane >> 4) * 8 + j;
    const int klog = ((s & 7) << 4) | (s >> 3);
    const int n = nt * 16 + (lane & 15);
    Wt2p[i] = ldinb(mW2, ((size_t)l * HD + klog) * HD + n, mode);
    Wtu1[i] = ldinb(uW1, ((size_t)l * HD + klog) * HD + n, mode);
    Wtu2p[i] = ldinb(uW2, ((size_t)l * HD + klog) * HD + n, mode);
  }
  for (int i = tid; i < PANEL; i += stride) {
    const int nt = i / 2048, ks = (i % 2048) / 512;
    const int lane = (i % 512) / 8, j = i % 8;
    const int s = ks * 32 + (lane >> 4) * 8 + j;
    const int klog = ((s & 7) << 4) | (s >> 3);
    const int n = nt * 16 + (lane & 15);
    Wto1[i] = ldinb(oW1, (size_t)klog * HD + n, mode);
    Wto2p[i] = ldinb(oW2, (size_t)klog * HD + n, mode);
  }
}

// ---------------- feat init (slot order) ----------------
__global__ __launch_bounds__(256) void k_featinit(const void* __restrict__ nemb,
                                                  const int* __restrict__ flagp,
                                                  u16* __restrict__ feat) {
  const int mode = *flagp;
  const int i = blockIdx.x * 256 + threadIdx.x;
  const int g = i & 15;
  u32 ou[4];
#pragma unroll
  for (int p = 0; p < 4; p++) {
    u16 a = ldinb(nemb, (2 * p) * 16 + g, mode);
    u16 b = ldinb(nemb, (2 * p + 1) * 16 + g, mode);
    ou[p] = (u32)a | ((u32)b << 16);
  }
  ((int4*)feat)[i] = make_int4((int)ou[0], (int)ou[1], (int)ou[2], (int)ou[3]);
}

// ---------------- edge feature encode (sorted order, slot order) --------------
__global__ __launch_bounds__(256) void k_encode(const void* __restrict__ d,
                                                const int* __restrict__ eids,
                                                const void* __restrict__ We,
                                                const void* __restrict__ be,
                                                const int* __restrict__ flagp,
                                                u16* __restrict__ e) {
  const int mode = *flagp;
  __shared__ float sW[9 * HD];
  __shared__ float sb[HD];
  for (int i = threadIdx.x; i < 9 * HD; i += 256) sW[i] = ldinf(We, i, mode);
  for (int i = threadIdx.x; i < HD; i += 256) sb[i] = ldinf(be, i, mode);
  __syncthreads();
  const int spos = blockIdx.x * 256 + threadIdx.x;   // sorted position
  const float dv = ldinf(d, eids[spos], mode);
  float de[9];
#pragma unroll
  for (int k = 0; k < 4; k++) {
    float x = dv * (1.0f / (float)(1 << k));
    de[k] = __sinf(x);
    de[4 + k] = __cosf(x);
  }
  de[8] = dv;
  u16* erow = e + (size_t)spos * HD;
#pragma unroll
  for (int g = 0; g < 16; g++) {
    u32 ou[4];
#pragma unroll
    for (int p = 0; p < 4; p++) {
      float vv[2];
#pragma unroll
      for (int t = 0; t < 2; t++) {
        const int h = (2 * p + t) * 16 + g;
        float a = sb[h];
#pragma unroll
        for (int k = 0; k < 9; k++) a += de[k] * sW[k * HD + h];
        vv[t] = siluf(siluf(a));
      }
      ou[p] = pk2(vv[0], vv[1]);
    }
    ((int4*)erow)[g] = make_int4((int)ou[0], (int)ou[1], (int)ou[2], (int)ou[3]);
  }
}

// ---------------- edge message layer: MT=1 (16 edges/wave) for occupancy ------
__global__ __launch_bounds__(64, 5) void k_edge(
    const u16* __restrict__ feat, u16* __restrict__ e,
    const int* __restrict__ src_s, const int* __restrict__ dst_s,
    const u16* __restrict__ Wt1, const u16* __restrict__ Wt2p,
    const void* __restrict__ b1g, const void* __restrict__ b2g,
    const void* __restrict__ softW, const void* __restrict__ softb,
    const int* __restrict__ flagp, float* __restrict__ msum, int layer) {
  __shared__ __align__(16) short lM[16 * HD];
  __shared__ float swg[16];
  __shared__ int sdst[16];
  const int mode = *flagp;
  const int l = threadIdx.x;
  const int c = l & 15, kg = l >> 4;
  const int blk = blockIdx.x * 16;

  if (l < 16) sdst[l] = dst_s[blk + l];

  size_t offS[1], offD[1], offE[1];
  offS[0] = (size_t)src_s[blk + c] * HD;
  offD[0] = (size_t)dst_s[blk + c] * HD;
  offE[0] = (size_t)(blk + c) * HD;

  const u16* W1l = Wt1 + (size_t)layer * 3 * PANEL;
  const u16* W2l = Wt2p + (size_t)layer * PANEL;

  f32x4 acc[1][8];
  acc_zero<1>(acc);
  gemm_gp<1>(feat, offS, W1l, l, kg, acc);
  gemm_gp<1>(feat, offD, W1l + PANEL, l, kg, acc);
  gemm_gp<1>(e, offE, W1l + 2 * PANEL, l, kg, acc);

  float bias1[8];
#pragma unroll
  for (int nt = 0; nt < 8; nt++)
    bias1[nt] = ldinf(b1g, layer * HD + nt * 16 + c, mode);
  wave_pack<1, true>(lM, c, kg, acc, bias1);   // h1, slot order
  __syncthreads();

  acc_zero<1>(acc);
  wave_gemm_p<1>(lM, W2l, l, c, kg, acc);      // h1 @ W2
  __syncthreads();

  float bias2[8], swf[8];
#pragma unroll
  for (int nt = 0; nt < 8; nt++) {
    bias2[nt] = ldinf(b2g, layer * HD + nt * 16 + c, mode);
    swf[nt] = ldinf(softW, (size_t)layer * HD + nt * 16 + c, mode);
  }
  const float sbv = ldinf(softb, layer, mode);

  // ---- fused: pack m -> lM, gate, e += m (direct int4 RMW, granule c) ----
  float wred[4];
#pragma unroll
  for (int rr = 0; rr < 4; rr++) {
    const int row = kg * 4 + rr;
    int4* erow4 = (int4*)(e + (size_t)(blk + row) * HD);
    const int4 eo = erow4[c];
    const u32 eu[4] = {(u32)eo.x, (u32)eo.y, (u32)eo.z, (u32)eo.w};
    float mv[8];
    float wp = 0.f;
#pragma unroll
    for (int nt = 0; nt < 8; nt++) {
      mv[nt] = siluf(acc[0][nt][rr] + bias2[nt]);
      wp += mv[nt] * swf[nt];
    }
    u32 mo[4], ou[4];
#pragma unroll
    for (int p = 0; p < 4; p++) {
      mo[p] = pk2(mv[2 * p], mv[2 * p + 1]);
      ou[p] = pk2(bf2f((u16)(eu[p] & 0xffffu)) + mv[2 * p],
                  bf2f((u16)(eu[p] >> 16)) + mv[2 * p + 1]);
    }
    ((int4*)(lM + row * HD))[c ^ (row & 7)] =
        make_int4((int)mo[0], (int)mo[1], (int)mo[2], (int)mo[3]);
    erow4[c] = make_int4((int)ou[0], (int)ou[1], (int)ou[2], (int)ou[3]);
    wp += __shfl_xor(wp, 1);
    wp += __shfl_xor(wp, 2);
    wp += __shfl_xor(wp, 4);
    wp += __shfl_xor(wp, 8);
    wred[rr] = wp;
  }
#pragma unroll
  for (int rr = 0; rr < 4; rr++)
    if (c == rr) swg[kg * 4 + rr] = sigf(wred[rr] + sbv);
  __syncthreads();

  // ---- msum run-aggregation (lane l owns slots l and l+64) ----
  const int gM = ((l >> 3) << 3);
  const int em = l & 7;
  float a0 = 0.f, a1 = 0.f;
  int cur = sdst[0];
  for (int r = 0; r < 16; r++) {
    const int dn = sdst[r];
    if (dn != cur) {  // wave-uniform branch: flush run
      atomicAdd(&msum[(size_t)cur * HD + l], a0);
      atomicAdd(&msum[(size_t)cur * HD + l + 64], a1);
      a0 = 0.f; a1 = 0.f; cur = dn;
    }
    const int rx = (r & 7) << 3;
    const float wgr = swg[r];
    a0 += wgr * bf2f((u16)lM[r * HD + (gM ^ rx) + em]);
    a1 += wgr * bf2f((u16)lM[r * HD + (gM ^ rx) + 64 + em]);
  }
  atomicAdd(&msum[(size_t)cur * HD + l], a0);
  atomicAdd(&msum[(size_t)cur * HD + l + 64], a1);
}

// ---------------- node update layer: MT=2, fused residual, zeroes msum --------
__global__ __launch_bounds__(64, 4) void k_node(
    u16* __restrict__ feat, float* __restrict__ msum,
    const u16* __restrict__ Wtu1, const u16* __restrict__ Wtu2p,
    const void* __restrict__ b1g, const void* __restrict__ b2g,
    const int* __restrict__ flagp, int layer) {
  __shared__ __align__(16) short lA[32 * HD];
  const int mode = *flagp;
  const int l = threadIdx.x;
  const int c = l & 15, kg = l >> 4;
  short* lAw = lA;
  const int blkn = blockIdx.x * 32;
  const u16* W1l = Wtu1 + (size_t)layer * PANEL;
  const u16* W2l = Wtu2p + (size_t)layer * PANEL;
  float bias1[8], bias2[8];
#pragma unroll
  for (int nt = 0; nt < 8; nt++) {
    bias1[nt] = ldinf(b1g, layer * HD + nt * 16 + c, mode);
    bias2[nt] = ldinf(b2g, layer * HD + nt * 16 + c, mode);
  }
  // stage upd_in = feat + msum, then zero msum for the next layer
  const float4 z4 = make_float4(0.f, 0.f, 0.f, 0.f);
#pragma unroll
  for (int rp = 0; rp < 8; rp++) {
    const int r = rp * 4 + (l >> 4);
    const int g = l & 15;
    const int4 fv = ((const int4*)(feat + (size_t)(blkn + r) * HD))[g];
    const u32 uu[4] = {(u32)fv.x, (u32)fv.y, (u32)fv.z, (u32)fv.w};
    float4* mrow4 = (float4*)(msum + (size_t)(blkn + r) * HD);
    const float4 ma = mrow4[2 * g];
    const float4 mb = mrow4[2 * g + 1];
    mrow4[2 * g] = z4;
    mrow4[2 * g + 1] = z4;
    const float mm[8] = {ma.x, ma.y, ma.z, ma.w, mb.x, mb.y, mb.z, mb.w};
    u32 ou[4];
#pragma unroll
    for (int p = 0; p < 4; p++) {
      ou[p] = pk2(bf2f((u16)(uu[p] & 0xffffu)) + mm[2 * p],
                  bf2f((u16)(uu[p] >> 16)) + mm[2 * p + 1]);
    }
    ((int4*)(lAw + r * HD))[g ^ (r & 7)] =
        make_int4((int)ou[0], (int)ou[1], (int)ou[2], (int)ou[3]);
  }
  __syncthreads();
  f32x4 acc[2][8];
  acc_zero<2>(acc);
  wave_gemm_p<2>(lAw, W1l, l, c, kg, acc);
  __syncthreads();
  wave_pack<2, true>(lAw, c, kg, acc, bias1);
  __syncthreads();
  acc_zero<2>(acc);
  wave_gemm_p<2>(lAw, W2l, l, c, kg, acc);

  // fused residual: feat[row] granule c += (acc + bias2), direct int4 RMW
#pragma unroll
  for (int mt = 0; mt < 2; mt++) {
#pragma unroll
    for (int rr = 0; rr < 4; rr++) {
      const int row = mt * 16 + kg * 4 + rr;
      int4* frow4 = (int4*)(feat + (size_t)(blkn + row) * HD);
      const int4 fo = frow4[c];
      const u32 fu[4] = {(u32)fo.x, (u32)fo.y, (u32)fo.z, (u32)fo.w};
      u32 ou[4];
#pragma unroll
      for (int p = 0; p < 4; p++) {
        const float x0 = acc[mt][2 * p][rr] + bias2[2 * p];
        const float x1 = acc[mt][2 * p + 1][rr] + bias2[2 * p + 1];
        ou[p] = pk2(bf2f((u16)(fu[p] & 0xffffu)) + x0,
                    bf2f((u16)(fu[p] >> 16)) + x1);
      }
      frow4[c] = make_int4((int)ou[0], (int)ou[1], (int)ou[2], (int)ou[3]);
    }
  }
}

// ---------------- output MLP + readout: MT=2 ----------------
__global__ __launch_bounds__(64, 4) void k_out(
    const u16* __restrict__ feat, const int* __restrict__ seg,
    const u16* __restrict__ Wto1, const u16* __restrict__ Wto2p,
    const void* __restrict__ ob1, const void* __restrict__ ob2,
    const int* __restrict__ flagp,
    float* __restrict__ sacc, u32* __restrict__ mxacc, float* __restrict__ cnt) {
  __shared__ __align__(16) short lA[32 * HD];
  __shared__ int sseg[32];
  const int mode = *flagp;
  const int l = threadIdx.x;
  const int c = l & 15, kg = l >> 4;
  short* lAw = lA;
  const int blkn = blockIdx.x * 32;
  float bias1[8], bias2[8];
#pragma unroll
  for (int nt = 0; nt < 8; nt++) {
    bias1[nt] = ldinf(ob1, nt * 16 + c, mode);
    bias2[nt] = ldinf(ob2, nt * 16 + c, mode);
  }
#pragma unroll
  for (int rp = 0; rp < 8; rp++) {
    const int r = rp * 4 + (l >> 4);
    const int g = l & 15;
    ((int4*)(lAw + r * HD))[g ^ (r & 7)] =
        ((const int4*)(feat + (size_t)(blkn + r) * HD))[g];
  }
  if (l < 32) sseg[l] = seg[blkn + l];
  __syncthreads();
  f32x4 acc[2][8];
  acc_zero<2>(acc);
  wave_gemm_p<2>(lAw, Wto1, l, c, kg, acc);
  __syncthreads();
  wave_pack<2, true>(lAw, c, kg, acc, bias1);
  __syncthreads();
  acc_zero<2>(acc);
  wave_gemm_p<2>(lAw, Wto2p, l, c, kg, acc);
  __syncthreads();
  wave_pack<2, false>(lAw, c, kg, acc, bias2);
  __syncthreads();

  // lane l owns u32 position l (slots 2l, 2l+1); sacc/mxacc slot order
  const int gL = l >> 2;
  const int eoff = (l & 3) * 2;
  const bool uniform = (sseg[0] == sseg[31]);
  if (uniform) {
    const int g = sseg[0];
    float s1 = 0.f, s2 = 0.f, x1 = -3.402823e38f, x2 = -3.402823e38f;
#pragma unroll 4
    for (int r = 0; r < 32; r++) {
      const u32 mv = *(const u32*)&lAw[r * HD + ((gL ^ (r & 7)) << 3) + eoff];
      const float v1 = bf2f((u16)(mv & 0xffffu));
      const float v2 = bf2f((u16)(mv >> 16));
      s1 += v1; s2 += v2;
      x1 = fmaxf(x1, v1); x2 = fmaxf(x2, v2);
    }
    atomicAdd(&sacc[(size_t)g * HD + 2 * l], s1);
    atomicAdd(&sacc[(size_t)g * HD + 2 * l + 1], s2);
    atomicMax(&mxacc[(size_t)g * HD + 2 * l], ordu(x1));
    atomicMax(&mxacc[(size_t)g * HD + 2 * l + 1], ordu(x2));
    if (l == 0) atomicAdd(&cnt[g], 32.0f);
  } else {
    if (l < 32) atomicAdd(&cnt[sseg[l]], 1.0f);
#pragma unroll 4
    for (int r = 0; r < 32; r++) {
      const u32 mv = *(const u32*)&lAw[r * HD + ((gL ^ (r & 7)) << 3) + eoff];
      const float v1 = bf2f((u16)(mv & 0xffffu));
      const float v2 = bf2f((u16)(mv >> 16));
      const int g = sseg[r];
      atomicAdd(&sacc[(size_t)g * HD + 2 * l], v1);
      atomicAdd(&sacc[(size_t)g * HD + 2 * l + 1], v2);
      atomicMax(&mxacc[(size_t)g * HD + 2 * l], ordu(v1));
      atomicMax(&mxacc[(size_t)g * HD + 2 * l + 1], ordu(v2));
    }
  }
}

// ---------------- finalize: un-permute slot order -> h order ------------------
__global__ __launch_bounds__(256) void k_final(const float* __restrict__ sacc,
                                               const u32* __restrict__ mxacc,
                                               const float* __restrict__ cnt,
                                               const int* __restrict__ flagp,
                                               void* __restrict__ out) {
  const int mode = *flagp;
  const int i = blockIdx.x * 256 + threadIdx.x;
  const int b = i / 384, j = i % 384;
  float v;
  if (j < HD) {
    const int p = ((j & 15) << 3) | (j >> 4);
    v = sacc[b * HD + p];
  } else if (j < 2 * HD) {
    const int t = j - HD;
    const int p = ((t & 15) << 3) | (t >> 4);
    v = sacc[b * HD + p] / fmaxf(cnt[b], 1.0f);
  } else {
    const int t = j - 2 * HD;
    const int p = ((t & 15) << 3) | (t >> 4);
    u32 u = mxacc[b * HD + p];
    u32 bits = (u >> 31) ? (u ^ 0x80000000u) : ~u;
    v = __uint_as_float(bits);
  }
  if (mode) ((float*)out)[i] = v;
  else ((u16*)out)[i] = f2bf(v);
}

extern "C" void kernel_launch(void* const* d_in, const int* in_sizes, int n_in,
                              void* d_out, int out_size, void* d_ws, size_t ws_size,
                              hipStream_t stream) {
  const void* d_d = d_in[0];
  const int* src = (const int*)d_in[1];
  const int* dst = (const int*)d_in[2];
  const int* seg = (const int*)d_in[3];
  const void* nemb = d_in[4];
  const void* We = d_in[5];
  const void* be = d_in[6];
  const void* mW1 = d_in[7];
  const void* mb1 = d_in[8];
  const void* mW2 = d_in[9];
  const void* mb2 = d_in[10];
  const void* sW = d_in[11];
  const void* sb = d_in[12];
  const void* uW1 = d_in[13];
  const void* ub1 = d_in[14];
  const void* uW2 = d_in[15];
  const void* ub2 = d_in[16];
  const void* oW1 = d_in[17];
  const void* ob1 = d_in[18];
  const void* oW2 = d_in[19];
  const void* ob2 = d_in[20];

  char* ws = (char*)d_ws;
  const size_t OFF_E = 0;
  const size_t OFF_MSUM = OFF_E + (size_t)NE * HD * 2;
  const size_t OFF_FEAT = OFF_MSUM + (size_t)NN * HD * 4;
  const size_t OFF_SACC = OFF_FEAT + (size_t)NN * HD * 2;
  const size_t OFF_MX = OFF_SACC + (size_t)NB * HD * 4;
  const size_t OFF_CNT = OFF_MX + (size_t)NB * HD * 4;
  const size_t OFF_DEG = OFF_CNT + 1024;
  const size_t OFF_ROWPTR = OFF_DEG + (size_t)NN * 4;
  const size_t OFF_CURSOR = OFF_ROWPTR + (size_t)(NN + 2) * 4;
  const size_t OFF_EIDS = OFF_CURSOR + (size_t)NN * 4;
  const size_t OFF_SRCS = OFF_EIDS + (size_t)NE * 4;
  const size_t OFF_DSTS = OFF_SRCS + (size_t)NE * 4;
  const size_t OFF_WT1 = OFF_DSTS + (size_t)NE * 4;
  const size_t OFF_WT2P = OFF_WT1 + (size_t)NL * 3 * PANEL * 2;
  const size_t OFF_WTU1 = OFF_WT2P + (size_t)NL * PANEL * 2;
  const size_t OFF_WTU2P = OFF_WTU1 + (size_t)NL * PANEL * 2;
  const size_t OFF_WTO1 = OFF_WTU2P + (size_t)NL * PANEL * 2;
  const size_t OFF_WTO2P = OFF_WTO1 + (size_t)PANEL * 2;
  const size_t OFF_FLAG = OFF_WTO2P + (size_t)PANEL * 2;

  u16* e = (u16*)(ws + OFF_E);
  float* msum = (float*)(ws + OFF_MSUM);
  u16* feat = (u16*)(ws + OFF_FEAT);
  float* sacc = (float*)(ws + OFF_SACC);
  u32* mx = (u32*)(ws + OFF_MX);
  float* cnt = (float*)(ws + OFF_CNT);
  u32* deg = (u32*)(ws + OFF_DEG);
  int* rowptr = (int*)(ws + OFF_ROWPTR);
  int* cursor = (int*)(ws + OFF_CURSOR);
  int* eids = (int*)(ws + OFF_EIDS);
  int* src_s = (int*)(ws + OFF_SRCS);
  int* dst_s = (int*)(ws + OFF_DSTS);
  u16* Wt1 = (u16*)(ws + OFF_WT1);
  u16* Wt2p = (u16*)(ws + OFF_WT2P);
  u16* Wtu1 = (u16*)(ws + OFF_WTU1);
  u16* Wtu2p = (u16*)(ws + OFF_WTU2P);
  u16* Wto1 = (u16*)(ws + OFF_WTO1);
  u16* Wto2p = (u16*)(ws + OFF_WTO2P);
  int* flag = (int*)(ws + OFF_FLAG);

  // zero sacc + mx + cnt + deg (contiguous region)
  hipMemsetAsync(ws + OFF_SACC, 0,
                 (size_t)NB * HD * 4 * 2 + 1024 + (size_t)NN * 4, stream);
  // zero msum once (layer 0); k_node re-zeroes it for subsequent layers
  hipMemsetAsync(msum, 0, (size_t)NN * HD * 4, stream);

  k_detect<<<1, 64, 0, stream>>>((const u16*)We, flag);
  k_prep<<<256, 256, 0, stream>>>(mW1, mW2, uW1, uW2, oW1, oW2, flag,
                                  Wt1, Wt2p, Wtu1, Wtu2p, Wto1, Wto2p);
  k_featinit<<<(NN * HD / 8) / 256, 256, 0, stream>>>(nemb, flag, feat);

  // CSR by dst (sorted edge order used everywhere)
  k_csr_deg<<<NE / 256, 256, 0, stream>>>(dst, deg);
  k_csr_scan<<<1, 1024, 0, stream>>>(deg, rowptr, cursor);
  k_csr_scatter<<<NE / 256, 256, 0, stream>>>(dst, src, cursor, eids, src_s, dst_s);

  k_encode<<<NE / 256, 256, 0, stream>>>(d_d, eids, We, be, flag, e);

  for (int l = 0; l < NL; l++) {
    k_edge<<<NE / 16, 64, 0, stream>>>(feat, e, src_s, dst_s, Wt1, Wt2p,
                                       mb1, mb2, sW, sb, flag, msum, l);
    k_node<<<NN / 32, 64, 0, stream>>>(feat, msum, Wtu1, Wtu2p, ub1, ub2, flag, l);
  }
  k_out<<<NN / 32, 64, 0, stream>>>(feat, seg, Wto1, Wto2p, ob1, ob2, flag, sacc, mx, cnt);
  k_final<<<(NB * 384) / 256, 256, 0, stream>>>(sacc, mx, cnt, flag, d_out);
}

// Round 13
// 749.823 us; speedup vs baseline: 1.0802x; 1.0802x over previous
//
#include <hip/hip_runtime.h>
#include <hip/hip_bf16.h>

#define NN 32768   // nodes
#define NB 256     // graphs
#define HD 128     // hidden
#define NL 4       // layers
#define NE 262144  // edges

typedef short bf16x8 __attribute__((ext_vector_type(8)));
typedef float f32x4 __attribute__((ext_vector_type(4)));
typedef unsigned short u16;
typedef unsigned int u32;

__device__ __forceinline__ float bf2f(u16 u) {
  return __uint_as_float(((u32)u) << 16);
}
__device__ __forceinline__ u16 f2bf(float f) {
  u32 x = __float_as_uint(f);
  u32 r = x + 0x7FFFu + ((x >> 16) & 1u);
  return (u16)(r >> 16);
}
// packed f32x2 -> bf16x2 via compiler cvt_pk (RNE)
__device__ __forceinline__ u32 pk2(float a, float b) {
  __hip_bfloat162 h = __float22bfloat162_rn(make_float2(a, b));
  return *reinterpret_cast<u32*>(&h);
}
__device__ __forceinline__ float siluf(float x) {
  return x * __builtin_amdgcn_rcpf(1.0f + __expf(-x));
}
__device__ __forceinline__ float sigf(float x) {
  return __builtin_amdgcn_rcpf(1.0f + __expf(-x));
}
__device__ __forceinline__ u32 ordu(float f) {
  u32 b = __float_as_uint(f);
  return (b & 0x80000000u) ? ~b : (b | 0x80000000u);
}

// ---- adaptive input loads: mode 1 = f32 inputs, mode 0 = bf16 inputs ----
__device__ __forceinline__ float ldinf(const void* p, size_t i, int mode) {
  return mode ? ((const float*)p)[i] : bf2f(((const u16*)p)[i]);
}
__device__ __forceinline__ u16 ldinb(const void* p, size_t i, int mode) {
  return mode ? f2bf(((const float*)p)[i]) : ((const u16*)p)[i];
}

// ---- dtype detector (confirmed mode=1/f32; kept as cheap guard) ----
__global__ void k_detect(const u16* __restrict__ Weraw, int* __restrict__ flag) {
  if (threadIdx.x == 0 && blockIdx.x == 0) {
    int cnt = 0;
    for (int i = 0; i < 256; i++) {
      u16 u = Weraw[2 * i];
      u32 e = (u >> 7) & 0xFFu;
      if (e >= 112u && e <= 126u) cnt++;
    }
    *flag = (cnt >= 128) ? 0 : 1;
  }
}

// ================= SLOT ORDER =================
// All 128-wide feature rows (e, feat, msum, sacc/mxacc) are in "slot order":
// position s holds feature h = (s&7)*16 + (s>>3) — wave_pack's natural output.
// Weight panels fold the permutation: klog = ((s&7)<<4)|(s>>3).
// Lane l's GEMM output for row R, cols {nt*16+c} == slots {8c..8c+7} == int4
// granule c of the row  =>  epilogue RMWs are direct int4 ops, no shuffles.
// ================= SORTED EDGES + XCD CHUNKING =================
// Edge arrays are dst-sorted (CSR order). Block indices of k_edge/k_node/k_out
// are chunk-swizzled: blk = (bid%8)*(grid/8) + bid/8 — each XCD owns a
// contiguous edge range == contiguous dst-node slab, so feat[dst] gathers,
// msum atomics, and the k_node consumption stay XCD-L2-local.

// ---------------- CSR build (by dst) ----------------
__global__ __launch_bounds__(256) void k_csr_deg(const int* __restrict__ dstp,
                                                 u32* __restrict__ deg) {
  const int i = blockIdx.x * 256 + threadIdx.x;
  atomicAdd(&deg[dstp[i]], 1u);
}

__global__ __launch_bounds__(1024) void k_csr_scan(const u32* __restrict__ deg,
                                                   int* __restrict__ rowptr,
                                                   int* __restrict__ cursor) {
  __shared__ int part[1024];
  const int t = threadIdx.x;
  int loc[32];
  int s = 0;
#pragma unroll
  for (int j = 0; j < 32; j++) { loc[j] = s; s += (int)deg[t * 32 + j]; }
  part[t] = s;
  __syncthreads();
  int inc = s;
  for (int off = 1; off < 1024; off <<= 1) {
    int tmp = (t >= off) ? part[t - off] : 0;
    __syncthreads();
    part[t] += tmp;
    __syncthreads();
  }
  const int base = part[t] - inc;
#pragma unroll
  for (int j = 0; j < 32; j++) {
    rowptr[t * 32 + j] = base + loc[j];
    cursor[t * 32 + j] = base + loc[j];
  }
  if (t == 1023) rowptr[NN] = part[1023];
}

__global__ __launch_bounds__(256) void k_csr_scatter(const int* __restrict__ dstp,
                                                     const int* __restrict__ srcp,
                                                     int* __restrict__ cursor,
                                                     int* __restrict__ eids,
                                                     int* __restrict__ src_s,
                                                     int* __restrict__ dst_s) {
  const int i = blockIdx.x * 256 + threadIdx.x;
  const int d = dstp[i];
  const int pos = atomicAdd(&cursor[d], 1);
  eids[pos] = i;
  src_s[pos] = srcp[i];
  dst_s[pos] = d;
}

// ---------------- per-wave GEMM pieces ----------------
// Wave tile: MT*16 rows x 128 cols, mfma_f32_16x16x32_bf16.
// A-frag: lane l holds A[row=(l&15)+16*mt][slot=(l>>4)*8+j]  (16B contiguous)
// B PACKED: Bp[((nt*4+ks)*64 + lane)*8 + j] = W[perm(slot)][col=nt*16+(lane&15)]
//   => every b-load is one CONTIGUOUS 1KB segment across the wave.
// C/D: col = lane&15, row = (lane>>4)*4 + reg  (m89-verified)
// LDS tile: [rows][128 shorts], XOR-swizzled 16B granules (g ^= row&7).
#define PANEL 16384  // shorts per packed 128x128 weight panel

template <int MT>
__device__ __forceinline__ void acc_zero(f32x4 (&acc)[MT][8]) {
#pragma unroll
  for (int mt = 0; mt < MT; mt++)
#pragma unroll
    for (int nt = 0; nt < 8; nt++) acc[mt][nt] = f32x4{0.f, 0.f, 0.f, 0.f};
}

template <int MT>
__device__ __forceinline__ void gemm_gp(const u16* __restrict__ A0,
                                        const size_t* rowoff,
                                        const u16* __restrict__ Bp,
                                        int l, int kg, f32x4 (&acc)[MT][8]) {
#pragma unroll
  for (int ks = 0; ks < 4; ks++) {
    bf16x8 a[MT];
#pragma unroll
    for (int mt = 0; mt < MT; mt++)
      a[mt] = *(const bf16x8*)&A0[rowoff[mt] + ks * 32 + kg * 8];
#pragma unroll
    for (int nt = 0; nt < 8; nt++) {
      bf16x8 b = *(const bf16x8*)&Bp[(size_t)((nt * 4 + ks) * 64 + l) * 8];
#pragma unroll
      for (int mt = 0; mt < MT; mt++)
        acc[mt][nt] = __builtin_amdgcn_mfma_f32_16x16x32_bf16(a[mt], b, acc[mt][nt], 0, 0, 0);
    }
  }
}

template <int MT>
__device__ __forceinline__ void wave_gemm_p(const short* lAw, const u16* __restrict__ Bp,
                                            int l, int c, int kg, f32x4 (&acc)[MT][8]) {
#pragma unroll
  for (int ks = 0; ks < 4; ks++) {
    bf16x8 a[MT];
#pragma unroll
    for (int mt = 0; mt < MT; mt++) {
      const int r = mt * 16 + c;
      const int k = ks * 32 + kg * 8;
      a[mt] = *(const bf16x8*)&lAw[r * HD + (k ^ ((r & 7) << 3))];
    }
#pragma unroll
    for (int nt = 0; nt < 8; nt++) {
      bf16x8 b = *(const bf16x8*)&Bp[(size_t)((nt * 4 + ks) * 64 + l) * 8];
#pragma unroll
      for (int mt = 0; mt < MT; mt++)
        acc[mt][nt] = __builtin_amdgcn_mfma_f32_16x16x32_bf16(a[mt], b, acc[mt][nt], 0, 0, 0);
    }
  }
}

template <int MT, bool SILU>
__device__ __forceinline__ void wave_pack(short* lAw, int c, int kg,
                                          f32x4 (&acc)[MT][8], const float* bias) {
#pragma unroll
  for (int mt = 0; mt < MT; mt++) {
#pragma unroll
    for (int rr = 0; rr < 4; rr++) {
      const int row = mt * 16 + kg * 4 + rr;
      u32 ou[4];
#pragma unroll
      for (int p = 0; p < 4; p++) {
        float x0 = acc[mt][2 * p][rr] + bias[2 * p];
        float x1 = acc[mt][2 * p + 1][rr] + bias[2 * p + 1];
        if (SILU) { x0 = siluf(x0); x1 = siluf(x1); }
        ou[p] = pk2(x0, x1);
      }
      ((int4*)(lAw + row * HD))[c ^ (row & 7)] =
          make_int4((int)ou[0], (int)ou[1], (int)ou[2], (int)ou[3]);
    }
  }
}

// ---------------- weight prep: pack panels, fold slot permutation -------------
__global__ __launch_bounds__(256) void k_prep(
    const void* __restrict__ mW1, const void* __restrict__ mW2,
    const void* __restrict__ uW1, const void* __restrict__ uW2,
    const void* __restrict__ oW1, const void* __restrict__ oW2,
    const int* __restrict__ flagp,
    u16* __restrict__ Wt1, u16* __restrict__ Wt2p,
    u16* __restrict__ Wtu1, u16* __restrict__ Wtu2p,
    u16* __restrict__ Wto1, u16* __restrict__ Wto2p) {
  const int mode = *flagp;
  const int tid = blockIdx.x * blockDim.x + threadIdx.x;
  const int stride = gridDim.x * blockDim.x;
  for (int i = tid; i < NL * 3 * PANEL; i += stride) {
    const int l = i / (3 * PANEL), r = i % (3 * PANEL);
    const int chunk = r / PANEL, r2 = r % PANEL;
    const int nt = r2 / 2048, ks = (r2 % 2048) / 512;
    const int lane = (r2 % 512) / 8, j = r2 % 8;
    const int s = ks * 32 + (lane >> 4) * 8 + j;
    const int klog = ((s & 7) << 4) | (s >> 3);
    const int n = nt * 16 + (lane & 15);
    Wt1[i] = ldinb(mW1, ((size_t)l * 384 + chunk * 128 + klog) * HD + n, mode);
  }
  for (int i = tid; i < NL * PANEL; i += stride) {
    const int l = i / PANEL, r = i % PANEL;
    const int nt = r / 2048, ks = (r % 2048) / 512;
    const int lane = (r % 512) / 8, j = r % 8;
    const int s = ks * 32 + (lane >> 4) * 8 + j;
    const int klog = ((s & 7) << 4) | (s >> 3);
    const int n = nt * 16 + (lane & 15);
    Wt2p[i] = ldinb(mW2, ((size_t)l * HD + klog) * HD + n, mode);
    Wtu1[i] = ldinb(uW1, ((size_t)l * HD + klog) * HD + n, mode);
    Wtu2p[i] = ldinb(uW2, ((size_t)l * HD + klog) * HD + n, mode);
  }
  for (int i = tid; i < PANEL; i += stride) {
    const int nt = i / 2048, ks = (i % 2048) / 512;
    const int lane = (i % 512) / 8, j = i % 8;
    const int s = ks * 32 + (lane >> 4) * 8 + j;
    const int klog = ((s & 7) << 4) | (s >> 3);
    const int n = nt * 16 + (lane & 15);
    Wto1[i] = ldinb(oW1, (size_t)klog * HD + n, mode);
    Wto2p[i] = ldinb(oW2, (size_t)klog * HD + n, mode);
  }
}

// ---------------- feat init (slot order) ----------------
__global__ __launch_bounds__(256) void k_featinit(const void* __restrict__ nemb,
                                                  const int* __restrict__ flagp,
                                                  u16* __restrict__ feat) {
  const int mode = *flagp;
  const int i = blockIdx.x * 256 + threadIdx.x;
  const int g = i & 15;
  u32 ou[4];
#pragma unroll
  for (int p = 0; p < 4; p++) {
    u16 a = ldinb(nemb, (2 * p) * 16 + g, mode);
    u16 b = ldinb(nemb, (2 * p + 1) * 16 + g, mode);
    ou[p] = (u32)a | ((u32)b << 16);
  }
  ((int4*)feat)[i] = make_int4((int)ou[0], (int)ou[1], (int)ou[2], (int)ou[3]);
}

// ---------------- edge feature encode (sorted order, slot order) --------------
__global__ __launch_bounds__(256) void k_encode(const void* __restrict__ d,
                                                const int* __restrict__ eids,
                                                const void* __restrict__ We,
                                                const void* __restrict__ be,
                                                const int* __restrict__ flagp,
                                                u16* __restrict__ e) {
  const int mode = *flagp;
  __shared__ float sW[9 * HD];
  __shared__ float sb[HD];
  for (int i = threadIdx.x; i < 9 * HD; i += 256) sW[i] = ldinf(We, i, mode);
  for (int i = threadIdx.x; i < HD; i += 256) sb[i] = ldinf(be, i, mode);
  __syncthreads();
  const int spos = blockIdx.x * 256 + threadIdx.x;   // sorted position
  const float dv = ldinf(d, eids[spos], mode);
  float de[9];
#pragma unroll
  for (int k = 0; k < 4; k++) {
    float x = dv * (1.0f / (float)(1 << k));
    de[k] = __sinf(x);
    de[4 + k] = __cosf(x);
  }
  de[8] = dv;
  u16* erow = e + (size_t)spos * HD;
#pragma unroll
  for (int g = 0; g < 16; g++) {
    u32 ou[4];
#pragma unroll
    for (int p = 0; p < 4; p++) {
      float vv[2];
#pragma unroll
      for (int t = 0; t < 2; t++) {
        const int h = (2 * p + t) * 16 + g;
        float a = sb[h];
#pragma unroll
        for (int k = 0; k < 9; k++) a += de[k] * sW[k * HD + h];
        vv[t] = siluf(siluf(a));
      }
      ou[p] = pk2(vv[0], vv[1]);
    }
    ((int4*)erow)[g] = make_int4((int)ou[0], (int)ou[1], (int)ou[2], (int)ou[3]);
  }
}

// ---------------- edge message layer: MT=2, dst-sorted, XCD-chunked -----------
__global__ __launch_bounds__(64, 4) void k_edge(
    const u16* __restrict__ feat, u16* __restrict__ e,
    const int* __restrict__ src_s, const int* __restrict__ dst_s,
    const u16* __restrict__ Wt1, const u16* __restrict__ Wt2p,
    const void* __restrict__ b1g, const void* __restrict__ b2g,
    const void* __restrict__ softW, const void* __restrict__ softb,
    const int* __restrict__ flagp, float* __restrict__ msum, int layer) {
  __shared__ __align__(16) short lM[32 * HD];
  __shared__ float swg[32];
  __shared__ int sdst[32];
  const int mode = *flagp;
  const int l = threadIdx.x;
  const int c = l & 15, kg = l >> 4;
  // XCD-chunked bijective swizzle (grid = 8192 = 8 x 1024)
  const int bid = (int)blockIdx.x;
  const int blk = (((bid & 7) << 10) | (bid >> 3)) * 32;

  if (l < 32) sdst[l] = dst_s[blk + l];

  size_t offS[2], offD[2], offE[2];
#pragma unroll
  for (int mt = 0; mt < 2; mt++) {
    const int eidx = blk + mt * 16 + c;
    offS[mt] = (size_t)src_s[eidx] * HD;
    offD[mt] = (size_t)dst_s[eidx] * HD;
    offE[mt] = (size_t)eidx * HD;
  }

  const u16* W1l = Wt1 + (size_t)layer * 3 * PANEL;
  const u16* W2l = Wt2p + (size_t)layer * PANEL;
  float bias1[8], bias2[8], swf[8];
#pragma unroll
  for (int nt = 0; nt < 8; nt++) {
    bias1[nt] = ldinf(b1g, layer * HD + nt * 16 + c, mode);
    bias2[nt] = ldinf(b2g, layer * HD + nt * 16 + c, mode);
    swf[nt] = ldinf(softW, (size_t)layer * HD + nt * 16 + c, mode);
  }
  const float sbv = ldinf(softb, layer, mode);

  f32x4 acc[2][8];
  acc_zero<2>(acc);
  gemm_gp<2>(feat, offS, W1l, l, kg, acc);
  gemm_gp<2>(feat, offD, W1l + PANEL, l, kg, acc);
  gemm_gp<2>(e, offE, W1l + 2 * PANEL, l, kg, acc);
  wave_pack<2, true>(lM, c, kg, acc, bias1);   // h1, slot order
  __syncthreads();

  acc_zero<2>(acc);
  wave_gemm_p<2>(lM, W2l, l, c, kg, acc);      // h1 @ W2
  __syncthreads();

  // ---- fused: pack m -> lM, gate, e += m (direct int4 RMW, granule c) ----
  float wred[2][4];
#pragma unroll
  for (int mt = 0; mt < 2; mt++) {
#pragma unroll
    for (int rr = 0; rr < 4; rr++) {
      const int row = mt * 16 + kg * 4 + rr;
      int4* erow4 = (int4*)(e + (size_t)(blk + row) * HD);
      const int4 eo = erow4[c];
      const u32 eu[4] = {(u32)eo.x, (u32)eo.y, (u32)eo.z, (u32)eo.w};
      float mv[8];
      float wp = 0.f;
#pragma unroll
      for (int nt = 0; nt < 8; nt++) {
        mv[nt] = siluf(acc[mt][nt][rr] + bias2[nt]);
        wp += mv[nt] * swf[nt];
      }
      u32 mo[4], ou[4];
#pragma unroll
      for (int p = 0; p < 4; p++) {
        mo[p] = pk2(mv[2 * p], mv[2 * p + 1]);
        ou[p] = pk2(bf2f((u16)(eu[p] & 0xffffu)) + mv[2 * p],
                    bf2f((u16)(eu[p] >> 16)) + mv[2 * p + 1]);
      }
      ((int4*)(lM + row * HD))[c ^ (row & 7)] =
          make_int4((int)mo[0], (int)mo[1], (int)mo[2], (int)mo[3]);
      erow4[c] = make_int4((int)ou[0], (int)ou[1], (int)ou[2], (int)ou[3]);
      wp += __shfl_xor(wp, 1);
      wp += __shfl_xor(wp, 2);
      wp += __shfl_xor(wp, 4);
      wp += __shfl_xor(wp, 8);
      wred[mt][rr] = wp;
    }
  }
#pragma unroll
  for (int mt = 0; mt < 2; mt++)
#pragma unroll
    for (int rr = 0; rr < 4; rr++)
      if (c == mt * 4 + rr) swg[mt * 16 + kg * 4 + rr] = sigf(wred[mt][rr] + sbv);
  __syncthreads();

  // ---- msum run-aggregation (lane l owns slots l and l+64) ----
  const int gM = ((l >> 3) << 3);
  const int em = l & 7;
  float a0 = 0.f, a1 = 0.f;
  int cur = sdst[0];
  for (int r = 0; r < 32; r++) {
    const int dn = sdst[r];
    if (dn != cur) {  // wave-uniform branch: flush run
      atomicAdd(&msum[(size_t)cur * HD + l], a0);
      atomicAdd(&msum[(size_t)cur * HD + l + 64], a1);
      a0 = 0.f; a1 = 0.f; cur = dn;
    }
    const int rx = (r & 7) << 3;
    const float wgr = swg[r];
    a0 += wgr * bf2f((u16)lM[r * HD + (gM ^ rx) + em]);
    a1 += wgr * bf2f((u16)lM[r * HD + (gM ^ rx) + 64 + em]);
  }
  atomicAdd(&msum[(size_t)cur * HD + l], a0);
  atomicAdd(&msum[(size_t)cur * HD + l + 64], a1);
}

// ---------------- node update layer: MT=2, fused residual, zeroes msum --------
__global__ __launch_bounds__(64, 4) void k_node(
    u16* __restrict__ feat, float* __restrict__ msum,
    const u16* __restrict__ Wtu1, const u16* __restrict__ Wtu2p,
    const void* __restrict__ b1g, const void* __restrict__ b2g,
    const int* __restrict__ flagp, int layer) {
  __shared__ __align__(16) short lA[32 * HD];
  const int mode = *flagp;
  const int l = threadIdx.x;
  const int c = l & 15, kg = l >> 4;
  short* lAw = lA;
  // XCD-chunked swizzle (grid = 1024 = 8 x 128), aligned with k_edge's chunks
  const int bid = (int)blockIdx.x;
  const int blkn = (((bid & 7) << 7) | (bid >> 3)) * 32;
  const u16* W1l = Wtu1 + (size_t)layer * PANEL;
  const u16* W2l = Wtu2p + (size_t)layer * PANEL;
  float bias1[8], bias2[8];
#pragma unroll
  for (int nt = 0; nt < 8; nt++) {
    bias1[nt] = ldinf(b1g, layer * HD + nt * 16 + c, mode);
    bias2[nt] = ldinf(b2g, layer * HD + nt * 16 + c, mode);
  }
  // stage upd_in = feat + msum, then zero msum for the next layer
  const float4 z4 = make_float4(0.f, 0.f, 0.f, 0.f);
#pragma unroll
  for (int rp = 0; rp < 8; rp++) {
    const int r = rp * 4 + (l >> 4);
    const int g = l & 15;
    const int4 fv = ((const int4*)(feat + (size_t)(blkn + r) * HD))[g];
    const u32 uu[4] = {(u32)fv.x, (u32)fv.y, (u32)fv.z, (u32)fv.w};
    float4* mrow4 = (float4*)(msum + (size_t)(blkn + r) * HD);
    const float4 ma = mrow4[2 * g];
    const float4 mb = mrow4[2 * g + 1];
    mrow4[2 * g] = z4;
    mrow4[2 * g + 1] = z4;
    const float mm[8] = {ma.x, ma.y, ma.z, ma.w, mb.x, mb.y, mb.z, mb.w};
    u32 ou[4];
#pragma unroll
    for (int p = 0; p < 4; p++) {
      ou[p] = pk2(bf2f((u16)(uu[p] & 0xffffu)) + mm[2 * p],
                  bf2f((u16)(uu[p] >> 16)) + mm[2 * p + 1]);
    }
    ((int4*)(lAw + r * HD))[g ^ (r & 7)] =
        make_int4((int)ou[0], (int)ou[1], (int)ou[2], (int)ou[3]);
  }
  __syncthreads();
  f32x4 acc[2][8];
  acc_zero<2>(acc);
  wave_gemm_p<2>(lAw, W1l, l, c, kg, acc);
  __syncthreads();
  wave_pack<2, true>(lAw, c, kg, acc, bias1);
  __syncthreads();
  acc_zero<2>(acc);
  wave_gemm_p<2>(lAw, W2l, l, c, kg, acc);

  // fused residual: feat[row] granule c += (acc + bias2), direct int4 RMW
#pragma unroll
  for (int mt = 0; mt < 2; mt++) {
#pragma unroll
    for (int rr = 0; rr < 4; rr++) {
      const int row = mt * 16 + kg * 4 + rr;
      int4* frow4 = (int4*)(feat + (size_t)(blkn + row) * HD);
      const int4 fo = frow4[c];
      const u32 fu[4] = {(u32)fo.x, (u32)fo.y, (u32)fo.z, (u32)fo.w};
      u32 ou[4];
#pragma unroll
      for (int p = 0; p < 4; p++) {
        const float x0 = acc[mt][2 * p][rr] + bias2[2 * p];
        const float x1 = acc[mt][2 * p + 1][rr] + bias2[2 * p + 1];
        ou[p] = pk2(bf2f((u16)(fu[p] & 0xffffu)) + x0,
                    bf2f((u16)(fu[p] >> 16)) + x1);
      }
      frow4[c] = make_int4((int)ou[0], (int)ou[1], (int)ou[2], (int)ou[3]);
    }
  }
}

// ---------------- output MLP + readout: MT=2 ----------------
__global__ __launch_bounds__(64, 4) void k_out(
    const u16* __restrict__ feat, const int* __restrict__ seg,
    const u16* __restrict__ Wto1, const u16* __restrict__ Wto2p,
    const void* __restrict__ ob1, const void* __restrict__ ob2,
    const int* __restrict__ flagp,
    float* __restrict__ sacc, u32* __restrict__ mxacc, float* __restrict__ cnt) {
  __shared__ __align__(16) short lA[32 * HD];
  __shared__ int sseg[32];
  const int mode = *flagp;
  const int l = threadIdx.x;
  const int c = l & 15, kg = l >> 4;
  short* lAw = lA;
  const int bid = (int)blockIdx.x;
  const int blkn = (((bid & 7) << 7) | (bid >> 3)) * 32;
  float bias1[8], bias2[8];
#pragma unroll
  for (int nt = 0; nt < 8; nt++) {
    bias1[nt] = ldinf(ob1, nt * 16 + c, mode);
    bias2[nt] = ldinf(ob2, nt * 16 + c, mode);
  }
#pragma unroll
  for (int rp = 0; rp < 8; rp++) {
    const int r = rp * 4 + (l >> 4);
    const int g = l & 15;
    ((int4*)(lAw + r * HD))[g ^ (r & 7)] =
        ((const int4*)(feat + (size_t)(blkn + r) * HD))[g];
  }
  if (l < 32) sseg[l] = seg[blkn + l];
  __syncthreads();
  f32x4 acc[2][8];
  acc_zero<2>(acc);
  wave_gemm_p<2>(lAw, Wto1, l, c, kg, acc);
  __syncthreads();
  wave_pack<2, true>(lAw, c, kg, acc, bias1);
  __syncthreads();
  acc_zero<2>(acc);
  wave_gemm_p<2>(lAw, Wto2p, l, c, kg, acc);
  __syncthreads();
  wave_pack<2, false>(lAw, c, kg, acc, bias2);
  __syncthreads();

  // lane l owns u32 position l (slots 2l, 2l+1); sacc/mxacc slot order
  const int gL = l >> 2;
  const int eoff = (l & 3) * 2;
  const bool uniform = (sseg[0] == sseg[31]);
  if (uniform) {
    const int g = sseg[0];
    float s1 = 0.f, s2 = 0.f, x1 = -3.402823e38f, x2 = -3.402823e38f;
#pragma unroll 4
    for (int r = 0; r < 32; r++) {
      const u32 mv = *(const u32*)&lAw[r * HD + ((gL ^ (r & 7)) << 3) + eoff];
      const float v1 = bf2f((u16)(mv & 0xffffu));
      const float v2 = bf2f((u16)(mv >> 16));
      s1 += v1; s2 += v2;
      x1 = fmaxf(x1, v1); x2 = fmaxf(x2, v2);
    }
    atomicAdd(&sacc[(size_t)g * HD + 2 * l], s1);
    atomicAdd(&sacc[(size_t)g * HD + 2 * l + 1], s2);
    atomicMax(&mxacc[(size_t)g * HD + 2 * l], ordu(x1));
    atomicMax(&mxacc[(size_t)g * HD + 2 * l + 1], ordu(x2));
    if (l == 0) atomicAdd(&cnt[g], 32.0f);
  } else {
    if (l < 32) atomicAdd(&cnt[sseg[l]], 1.0f);
#pragma unroll 4
    for (int r = 0; r < 32; r++) {
      const u32 mv = *(const u32*)&lAw[r * HD + ((gL ^ (r & 7)) << 3) + eoff];
      const float v1 = bf2f((u16)(mv & 0xffffu));
      const float v2 = bf2f((u16)(mv >> 16));
      const int g = sseg[r];
      atomicAdd(&sacc[(size_t)g * HD + 2 * l], v1);
      atomicAdd(&sacc[(size_t)g * HD + 2 * l + 1], v2);
      atomicMax(&mxacc[(size_t)g * HD + 2 * l], ordu(v1));
      atomicMax(&mxacc[(size_t)g * HD + 2 * l + 1], ordu(v2));
    }
  }
}

// ---------------- finalize: un-permute slot order -> h order ------------------
__global__ __launch_bounds__(256) void k_final(const float* __restrict__ sacc,
                                               const u32* __restrict__ mxacc,
                                               const float* __restrict__ cnt,
                                               const int* __restrict__ flagp,
                                               void* __restrict__ out) {
  const int mode = *flagp;
  const int i = blockIdx.x * 256 + threadIdx.x;
  const int b = i / 384, j = i % 384;
  float v;
  if (j < HD) {
    const int p = ((j & 15) << 3) | (j >> 4);
    v = sacc[b * HD + p];
  } else if (j < 2 * HD) {
    const int t = j - HD;
    const int p = ((t & 15) << 3) | (t >> 4);
    v = sacc[b * HD + p] / fmaxf(cnt[b], 1.0f);
  } else {
    const int t = j - 2 * HD;
    const int p = ((t & 15) << 3) | (t >> 4);
    u32 u = mxacc[b * HD + p];
    u32 bits = (u >> 31) ? (u ^ 0x80000000u) : ~u;
    v = __uint_as_float(bits);
  }
  if (mode) ((float*)out)[i] = v;
  else ((u16*)out)[i] = f2bf(v);
}

extern "C" void kernel_launch(void* const* d_in, const int* in_sizes, int n_in,
                              void* d_out, int out_size, void* d_ws, size_t ws_size,
                              hipStream_t stream) {
  const void* d_d = d_in[0];
  const int* src = (const int*)d_in[1];
  const int* dst = (const int*)d_in[2];
  const int* seg = (const int*)d_in[3];
  const void* nemb = d_in[4];
  const void* We = d_in[5];
  const void* be = d_in[6];
  const void* mW1 = d_in[7];
  const void* mb1 = d_in[8];
  const void* mW2 = d_in[9];
  const void* mb2 = d_in[10];
  const void* sW = d_in[11];
  const void* sb = d_in[12];
  const void* uW1 = d_in[13];
  const void* ub1 = d_in[14];
  const void* uW2 = d_in[15];
  const void* ub2 = d_in[16];
  const void* oW1 = d_in[17];
  const void* ob1 = d_in[18];
  const void* oW2 = d_in[19];
  const void* ob2 = d_in[20];

  char* ws = (char*)d_ws;
  const size_t OFF_E = 0;
  const size_t OFF_MSUM = OFF_E + (size_t)NE * HD * 2;
  const size_t OFF_FEAT = OFF_MSUM + (size_t)NN * HD * 4;
  const size_t OFF_SACC = OFF_FEAT + (size_t)NN * HD * 2;
  const size_t OFF_MX = OFF_SACC + (size_t)NB * HD * 4;
  const size_t OFF_CNT = OFF_MX + (size_t)NB * HD * 4;
  const size_t OFF_DEG = OFF_CNT + 1024;
  const size_t OFF_ROWPTR = OFF_DEG + (size_t)NN * 4;
  const size_t OFF_CURSOR = OFF_ROWPTR + (size_t)(NN + 2) * 4;
  const size_t OFF_EIDS = OFF_CURSOR + (size_t)NN * 4;
  const size_t OFF_SRCS = OFF_EIDS + (size_t)NE * 4;
  const size_t OFF_DSTS = OFF_SRCS + (size_t)NE * 4;
  const size_t OFF_WT1 = OFF_DSTS + (size_t)NE * 4;
  const size_t OFF_WT2P = OFF_WT1 + (size_t)NL * 3 * PANEL * 2;
  const size_t OFF_WTU1 = OFF_WT2P + (size_t)NL * PANEL * 2;
  const size_t OFF_WTU2P = OFF_WTU1 + (size_t)NL * PANEL * 2;
  const size_t OFF_WTO1 = OFF_WTU2P + (size_t)NL * PANEL * 2;
  const size_t OFF_WTO2P = OFF_WTO1 + (size_t)PANEL * 2;
  const size_t OFF_FLAG = OFF_WTO2P + (size_t)PANEL * 2;

  u16* e = (u16*)(ws + OFF_E);
  float* msum = (float*)(ws + OFF_MSUM);
  u16* feat = (u16*)(ws + OFF_FEAT);
  float* sacc = (float*)(ws + OFF_SACC);
  u32* mx = (u32*)(ws + OFF_MX);
  float* cnt = (float*)(ws + OFF_CNT);
  u32* deg = (u32*)(ws + OFF_DEG);
  int* rowptr = (int*)(ws + OFF_ROWPTR);
  int* cursor = (int*)(ws + OFF_CURSOR);
  int* eids = (int*)(ws + OFF_EIDS);
  int* src_s = (int*)(ws + OFF_SRCS);
  int* dst_s = (int*)(ws + OFF_DSTS);
  u16* Wt1 = (u16*)(ws + OFF_WT1);
  u16* Wt2p = (u16*)(ws + OFF_WT2P);
  u16* Wtu1 = (u16*)(ws + OFF_WTU1);
  u16* Wtu2p = (u16*)(ws + OFF_WTU2P);
  u16* Wto1 = (u16*)(ws + OFF_WTO1);
  u16* Wto2p = (u16*)(ws + OFF_WTO2P);
  int* flag = (int*)(ws + OFF_FLAG);

  // zero sacc + mx + cnt + deg (contiguous region)
  hipMemsetAsync(ws + OFF_SACC, 0,
                 (size_t)NB * HD * 4 * 2 + 1024 + (size_t)NN * 4, stream);
  // zero msum once (layer 0); k_node re-zeroes it for subsequent layers
  hipMemsetAsync(msum, 0, (size_t)NN * HD * 4, stream);

  k_detect<<<1, 64, 0, stream>>>((const u16*)We, flag);
  k_prep<<<256, 256, 0, stream>>>(mW1, mW2, uW1, uW2, oW1, oW2, flag,
                                  Wt1, Wt2p, Wtu1, Wtu2p, Wto1, Wto2p);
  k_featinit<<<(NN * HD / 8) / 256, 256, 0, stream>>>(nemb, flag, feat);

  // CSR by dst (sorted edge order used everywhere)
  k_csr_deg<<<NE / 256, 256, 0, stream>>>(dst, deg);
  k_csr_scan<<<1, 1024, 0, stream>>>(deg, rowptr, cursor);
  k_csr_scatter<<<NE / 256, 256, 0, stream>>>(dst, src, cursor, eids, src_s, dst_s);

  k_encode<<<NE / 256, 256, 0, stream>>>(d_d, eids, We, be, flag, e);

  for (int l = 0; l < NL; l++) {
    k_edge<<<NE / 32, 64, 0, stream>>>(feat, e, src_s, dst_s, Wt1, Wt2p,
                                       mb1, mb2, sW, sb, flag, msum, l);
    k_node<<<NN / 32, 64, 0, stream>>>(feat, msum, Wtu1, Wtu2p, ub1, ub2, flag, l);
  }
  k_out<<<NN / 32, 64, 0, stream>>>(feat, seg, Wto1, Wto2p, ob1, ob2, flag, sacc, mx, cnt);
  k_final<<<(NB * 384) / 256, 256, 0, stream>>>(sacc, mx, cnt, flag, d_out);
}

// Round 14
// 741.539 us; speedup vs baseline: 1.0922x; 1.0112x over previous
//
#include <hip/hip_runtime.h>
#include <hip/hip_bf16.h>

#define NN 32768   // nodes
#define NB 256     // graphs
#define HD 128     // hidden
#define NL 4       // layers
#define NE 262144  // edges

typedef short bf16x8 __attribute__((ext_vector_type(8)));
typedef float f32x4 __attribute__((ext_vector_type(4)));
typedef unsigned short u16;
typedef unsigned int u32;

__device__ __forceinline__ float bf2f(u16 u) {
  return __uint_as_float(((u32)u) << 16);
}
__device__ __forceinline__ u16 f2bf(float f) {
  u32 x = __float_as_uint(f);
  u32 r = x + 0x7FFFu + ((x >> 16) & 1u);
  return (u16)(r >> 16);
}
// packed f32x2 -> bf16x2 via compiler cvt_pk (RNE)
__device__ __forceinline__ u32 pk2(float a, float b) {
  __hip_bfloat162 h = __float22bfloat162_rn(make_float2(a, b));
  return *reinterpret_cast<u32*>(&h);
}
__device__ __forceinline__ float siluf(float x) {
  return x * __builtin_amdgcn_rcpf(1.0f + __expf(-x));
}
__device__ __forceinline__ float sigf(float x) {
  return __builtin_amdgcn_rcpf(1.0f + __expf(-x));
}
__device__ __forceinline__ u32 ordu(float f) {
  u32 b = __float_as_uint(f);
  return (b & 0x80000000u) ? ~b : (b | 0x80000000u);
}

// ---- adaptive input loads: mode 1 = f32 inputs, mode 0 = bf16 inputs ----
__device__ __forceinline__ float ldinf(const void* p, size_t i, int mode) {
  return mode ? ((const float*)p)[i] : bf2f(((const u16*)p)[i]);
}
__device__ __forceinline__ u16 ldinb(const void* p, size_t i, int mode) {
  return mode ? f2bf(((const float*)p)[i]) : ((const u16*)p)[i];
}

// ---- dtype detector (confirmed mode=1/f32; kept as cheap guard) ----
__global__ void k_detect(const u16* __restrict__ Weraw, int* __restrict__ flag) {
  if (threadIdx.x == 0 && blockIdx.x == 0) {
    int cnt = 0;
    for (int i = 0; i < 256; i++) {
      u16 u = Weraw[2 * i];
      u32 e = (u >> 7) & 0xFFu;
      if (e >= 112u && e <= 126u) cnt++;
    }
    *flag = (cnt >= 128) ? 0 : 1;
  }
}

// ================= SLOT ORDER =================
// All 128-wide feature rows (e, feat, msum, sacc/mxacc) are in "slot order":
// position s holds feature h = (s&7)*16 + (s>>3) — wave_pack's natural output.
// Weight panels fold the permutation: klog = ((s&7)<<4)|(s>>3).
// Lane l's GEMM output for row R, cols {nt*16+c} == slots {8c..8c+7} == int4
// granule c of the row  =>  epilogue RMWs are direct int4 ops, no shuffles.
// ================= SORTED EDGES + XCD CHUNKING =================
// Edge arrays are dst-sorted (CSR order); block indices chunk-swizzled so each
// XCD owns a contiguous edge/node slab.
// ================= k_edge: 4-wave blocks, B in LDS =================
// 256-thread blocks stage each 32KB weight panel into LDS once; all 4 waves
// consume it as conflict-free ds_read_b128. A-gather fragments are pre-issued
// before each staging barrier so their latency hides under the stage+sync.

// ---------------- CSR build (by dst) ----------------
__global__ __launch_bounds__(256) void k_csr_deg(const int* __restrict__ dstp,
                                                 u32* __restrict__ deg) {
  const int i = blockIdx.x * 256 + threadIdx.x;
  atomicAdd(&deg[dstp[i]], 1u);
}

__global__ __launch_bounds__(1024) void k_csr_scan(const u32* __restrict__ deg,
                                                   int* __restrict__ rowptr,
                                                   int* __restrict__ cursor) {
  __shared__ int part[1024];
  const int t = threadIdx.x;
  int loc[32];
  int s = 0;
#pragma unroll
  for (int j = 0; j < 32; j++) { loc[j] = s; s += (int)deg[t * 32 + j]; }
  part[t] = s;
  __syncthreads();
  int inc = s;
  for (int off = 1; off < 1024; off <<= 1) {
    int tmp = (t >= off) ? part[t - off] : 0;
    __syncthreads();
    part[t] += tmp;
    __syncthreads();
  }
  const int base = part[t] - inc;
#pragma unroll
  for (int j = 0; j < 32; j++) {
    rowptr[t * 32 + j] = base + loc[j];
    cursor[t * 32 + j] = base + loc[j];
  }
  if (t == 1023) rowptr[NN] = part[1023];
}

__global__ __launch_bounds__(256) void k_csr_scatter(const int* __restrict__ dstp,
                                                     const int* __restrict__ srcp,
                                                     int* __restrict__ cursor,
                                                     int* __restrict__ eids,
                                                     int* __restrict__ src_s,
                                                     int* __restrict__ dst_s) {
  const int i = blockIdx.x * 256 + threadIdx.x;
  const int d = dstp[i];
  const int pos = atomicAdd(&cursor[d], 1);
  eids[pos] = i;
  src_s[pos] = srcp[i];
  dst_s[pos] = d;
}

// ---------------- per-wave GEMM pieces ----------------
// Wave tile: MT*16 rows x 128 cols, mfma_f32_16x16x32_bf16.
// A-frag: lane l holds A[row=(l&15)+16*mt][slot=(l>>4)*8+j]  (16B contiguous)
// B PACKED: Bp[((nt*4+ks)*64 + lane)*8 + j] = W[perm(slot)][col=nt*16+(lane&15)]
// C/D: col = lane&15, row = (lane>>4)*4 + reg  (m89-verified)
// LDS A tile: [rows][128 shorts], XOR-swizzled 16B granules (g ^= row&7).
#define PANEL 16384  // shorts per packed 128x128 weight panel

template <int MT>
__device__ __forceinline__ void acc_zero(f32x4 (&acc)[MT][8]) {
#pragma unroll
  for (int mt = 0; mt < MT; mt++)
#pragma unroll
    for (int nt = 0; nt < 8; nt++) acc[mt][nt] = f32x4{0.f, 0.f, 0.f, 0.f};
}

// pre-issue A-fragment loads (global gather) into registers
__device__ __forceinline__ void load_a2(const u16* __restrict__ A0,
                                        const size_t* rowoff, int kg,
                                        bf16x8 (&a)[2][4]) {
#pragma unroll
  for (int ks = 0; ks < 4; ks++)
#pragma unroll
    for (int mt = 0; mt < 2; mt++)
      a[mt][ks] = *(const bf16x8*)&A0[rowoff[mt] + ks * 32 + kg * 8];
}

// GEMM with A in regs, B from LDS-staged panel (conflict-free ds_read_b128)
__device__ __forceinline__ void gemm_lds2(const bf16x8 (&a)[2][4],
                                          const short* sB, int l,
                                          f32x4 (&acc)[2][8]) {
#pragma unroll
  for (int ks = 0; ks < 4; ks++)
#pragma unroll
    for (int nt = 0; nt < 8; nt++) {
      bf16x8 b = *(const bf16x8*)&sB[((nt * 4 + ks) * 64 + l) * 8];
#pragma unroll
      for (int mt = 0; mt < 2; mt++)
        acc[mt][nt] = __builtin_amdgcn_mfma_f32_16x16x32_bf16(a[mt][ks], b, acc[mt][nt], 0, 0, 0);
    }
}

// GEMM with A from swizzled LDS tile, B from pointer (global packed or LDS)
template <int MT>
__device__ __forceinline__ void wave_gemm_p(const short* lAw, const u16* __restrict__ Bp,
                                            int l, int c, int kg, f32x4 (&acc)[MT][8]) {
#pragma unroll
  for (int ks = 0; ks < 4; ks++) {
    bf16x8 a[MT];
#pragma unroll
    for (int mt = 0; mt < MT; mt++) {
      const int r = mt * 16 + c;
      const int k = ks * 32 + kg * 8;
      a[mt] = *(const bf16x8*)&lAw[r * HD + (k ^ ((r & 7) << 3))];
    }
#pragma unroll
    for (int nt = 0; nt < 8; nt++) {
      bf16x8 b = *(const bf16x8*)&Bp[(size_t)((nt * 4 + ks) * 64 + l) * 8];
#pragma unroll
      for (int mt = 0; mt < MT; mt++)
        acc[mt][nt] = __builtin_amdgcn_mfma_f32_16x16x32_bf16(a[mt], b, acc[mt][nt], 0, 0, 0);
    }
  }
}

template <int MT, bool SILU>
__device__ __forceinline__ void wave_pack(short* lAw, int c, int kg,
                                          f32x4 (&acc)[MT][8], const float* bias) {
#pragma unroll
  for (int mt = 0; mt < MT; mt++) {
#pragma unroll
    for (int rr = 0; rr < 4; rr++) {
      const int row = mt * 16 + kg * 4 + rr;
      u32 ou[4];
#pragma unroll
      for (int p = 0; p < 4; p++) {
        float x0 = acc[mt][2 * p][rr] + bias[2 * p];
        float x1 = acc[mt][2 * p + 1][rr] + bias[2 * p + 1];
        if (SILU) { x0 = siluf(x0); x1 = siluf(x1); }
        ou[p] = pk2(x0, x1);
      }
      ((int4*)(lAw + row * HD))[c ^ (row & 7)] =
          make_int4((int)ou[0], (int)ou[1], (int)ou[2], (int)ou[3]);
    }
  }
}

// 256 threads stage one 32KB packed panel into LDS (coalesced 16B per thread)
__device__ __forceinline__ void stage_panel(const u16* __restrict__ P,
                                            short* sB, int tid) {
#pragma unroll
  for (int it = 0; it < 8; it++) {
    const int idx = (it * 256 + tid) * 8;
    *(int4*)&sB[idx] = *(const int4*)&P[idx];
  }
}

// ---------------- weight prep: pack panels, fold slot permutation -------------
__global__ __launch_bounds__(256) void k_prep(
    const void* __restrict__ mW1, const void* __restrict__ mW2,
    const void* __restrict__ uW1, const void* __restrict__ uW2,
    const void* __restrict__ oW1, const void* __restrict__ oW2,
    const int* __restrict__ flagp,
    u16* __restrict__ Wt1, u16* __restrict__ Wt2p,
    u16* __restrict__ Wtu1, u16* __restrict__ Wtu2p,
    u16* __restrict__ Wto1, u16* __restrict__ Wto2p) {
  const int mode = *flagp;
  const int tid = blockIdx.x * blockDim.x + threadIdx.x;
  const int stride = gridDim.x * blockDim.x;
  for (int i = tid; i < NL * 3 * PANEL; i += stride) {
    const int l = i / (3 * PANEL), r = i % (3 * PANEL);
    const int chunk = r / PANEL, r2 = r % PANEL;
    const int nt = r2 / 2048, ks = (r2 % 2048) / 512;
    const int lane = (r2 % 512) / 8, j = r2 % 8;
    const int s = ks * 32 + (lane >> 4) * 8 + j;
    const int klog = ((s & 7) << 4) | (s >> 3);
    const int n = nt * 16 + (lane & 15);
    Wt1[i] = ldinb(mW1, ((size_t)l * 384 + chunk * 128 + klog) * HD + n, mode);
  }
  for (int i = tid; i < NL * PANEL; i += stride) {
    const int l = i / PANEL, r = i % PANEL;
    const int nt = r / 2048, ks = (r % 2048) / 512;
    const int lane = (r % 512) / 8, j = r % 8;
    const int s = ks * 32 + (lane >> 4) * 8 + j;
    const int klog = ((s & 7) << 4) | (s >> 3);
    const int n = nt * 16 + (lane & 15);
    Wt2p[i] = ldinb(mW2, ((size_t)l * HD + klog) * HD + n, mode);
    Wtu1[i] = ldinb(uW1, ((size_t)l * HD + klog) * HD + n, mode);
    Wtu2p[i] = ldinb(uW2, ((size_t)l * HD + klog) * HD + n, mode);
  }
  for (int i = tid; i < PANEL; i += stride) {
    const int nt = i / 2048, ks = (i % 2048) / 512;
    const int lane = (i % 512) / 8, j = i % 8;
    const int s = ks * 32 + (lane >> 4) * 8 + j;
    const int klog = ((s & 7) << 4) | (s >> 3);
    const int n = nt * 16 + (lane & 15);
    Wto1[i] = ldinb(oW1, (size_t)klog * HD + n, mode);
    Wto2p[i] = ldinb(oW2, (size_t)klog * HD + n, mode);
  }
}

// ---------------- feat init (slot order) ----------------
__global__ __launch_bounds__(256) void k_featinit(const void* __restrict__ nemb,
                                                  const int* __restrict__ flagp,
                                                  u16* __restrict__ feat) {
  const int mode = *flagp;
  const int i = blockIdx.x * 256 + threadIdx.x;
  const int g = i & 15;
  u32 ou[4];
#pragma unroll
  for (int p = 0; p < 4; p++) {
    u16 a = ldinb(nemb, (2 * p) * 16 + g, mode);
    u16 b = ldinb(nemb, (2 * p + 1) * 16 + g, mode);
    ou[p] = (u32)a | ((u32)b << 16);
  }
  ((int4*)feat)[i] = make_int4((int)ou[0], (int)ou[1], (int)ou[2], (int)ou[3]);
}

// ---------------- edge feature encode (sorted order, slot order) --------------
__global__ __launch_bounds__(256) void k_encode(const void* __restrict__ d,
                                                const int* __restrict__ eids,
                                                const void* __restrict__ We,
                                                const void* __restrict__ be,
                                                const int* __restrict__ flagp,
                                                u16* __restrict__ e) {
  const int mode = *flagp;
  __shared__ float sW[9 * HD];
  __shared__ float sb[HD];
  for (int i = threadIdx.x; i < 9 * HD; i += 256) sW[i] = ldinf(We, i, mode);
  for (int i = threadIdx.x; i < HD; i += 256) sb[i] = ldinf(be, i, mode);
  __syncthreads();
  const int spos = blockIdx.x * 256 + threadIdx.x;   // sorted position
  const float dv = ldinf(d, eids[spos], mode);
  float de[9];
#pragma unroll
  for (int k = 0; k < 4; k++) {
    float x = dv * (1.0f / (float)(1 << k));
    de[k] = __sinf(x);
    de[4 + k] = __cosf(x);
  }
  de[8] = dv;
  u16* erow = e + (size_t)spos * HD;
#pragma unroll
  for (int g = 0; g < 16; g++) {
    u32 ou[4];
#pragma unroll
    for (int p = 0; p < 4; p++) {
      float vv[2];
#pragma unroll
      for (int t = 0; t < 2; t++) {
        const int h = (2 * p + t) * 16 + g;
        float a = sb[h];
#pragma unroll
        for (int k = 0; k < 9; k++) a += de[k] * sW[k * HD + h];
        vv[t] = siluf(siluf(a));
      }
      ou[p] = pk2(vv[0], vv[1]);
    }
    ((int4*)erow)[g] = make_int4((int)ou[0], (int)ou[1], (int)ou[2], (int)ou[3]);
  }
}

// ---------------- edge message layer: 4-wave blocks, B staged in LDS ----------
__global__ __launch_bounds__(256, 2) void k_edge(
    const u16* __restrict__ feat, u16* __restrict__ e,
    const int* __restrict__ src_s, const int* __restrict__ dst_s,
    const u16* __restrict__ Wt1, const u16* __restrict__ Wt2p,
    const void* __restrict__ b1g, const void* __restrict__ b2g,
    const void* __restrict__ softW, const void* __restrict__ softb,
    const int* __restrict__ flagp, float* __restrict__ msum, int layer) {
  __shared__ __align__(16) short sB[PANEL];      // 32 KB staged B panel
  __shared__ __align__(16) short lM[128 * HD];   // 32 KB, 4 waves x 32 rows
  __shared__ float swg[128];
  __shared__ int sdst[128];
  const int mode = *flagp;
  const int tid = threadIdx.x;
  const int l = tid & 63, wid = tid >> 6;
  const int c = l & 15, kg = l >> 4;
  // XCD-chunked bijective swizzle (grid = 2048 = 8 x 256), 128 edges/block
  const int bid = (int)blockIdx.x;
  const int blkB = (((bid & 7) << 8) | (bid >> 3)) * 128;
  const int blk = blkB + wid * 32;               // this wave's 32 edges
  short* lMw = lM + wid * 32 * HD;
  float* swgw = swg + wid * 32;
  int* sdstw = sdst + wid * 32;

  if (l < 32) sdstw[l] = dst_s[blk + l];

  size_t offS[2], offD[2], offE[2];
#pragma unroll
  for (int mt = 0; mt < 2; mt++) {
    const int eidx = blk + mt * 16 + c;
    offS[mt] = (size_t)src_s[eidx] * HD;
    offD[mt] = (size_t)dst_s[eidx] * HD;
    offE[mt] = (size_t)eidx * HD;
  }

  const u16* W1l = Wt1 + (size_t)layer * 3 * PANEL;
  const u16* W2l = Wt2p + (size_t)layer * PANEL;
  float bias1[8], bias2[8], swf[8];
#pragma unroll
  for (int nt = 0; nt < 8; nt++) {
    bias1[nt] = ldinf(b1g, layer * HD + nt * 16 + c, mode);
    bias2[nt] = ldinf(b2g, layer * HD + nt * 16 + c, mode);
    swf[nt] = ldinf(softW, (size_t)layer * HD + nt * 16 + c, mode);
  }
  const float sbv = ldinf(softb, layer, mode);

  f32x4 acc[2][8];
  acc_zero<2>(acc);
  bf16x8 a[2][4];

  // ---- GEMM1 chunk 0 (feat[src]): A pre-issued, B staged under it ----
  load_a2(feat, offS, kg, a);
  stage_panel(W1l, sB, tid);
  __syncthreads();
  gemm_lds2(a, sB, l, acc);
  __syncthreads();
  // ---- chunk 1 (feat[dst]) ----
  load_a2(feat, offD, kg, a);
  stage_panel(W1l + PANEL, sB, tid);
  __syncthreads();
  gemm_lds2(a, sB, l, acc);
  __syncthreads();
  // ---- chunk 2 (e) ----
  load_a2(e, offE, kg, a);
  stage_panel(W1l + 2 * PANEL, sB, tid);
  __syncthreads();
  gemm_lds2(a, sB, l, acc);
  __syncthreads();

  // ---- stage W2 while packing h1 into own lM slice ----
  stage_panel(W2l, sB, tid);
  wave_pack<2, true>(lMw, c, kg, acc, bias1);   // h1, slot order
  __syncthreads();

  acc_zero<2>(acc);
  wave_gemm_p<2>(lMw, (const u16*)sB, l, c, kg, acc);  // h1 @ W2 (B in LDS)

  // ---- fused: pack m -> lMw, gate, e += m (direct int4 RMW, granule c) ----
  float wred[2][4];
#pragma unroll
  for (int mt = 0; mt < 2; mt++) {
#pragma unroll
    for (int rr = 0; rr < 4; rr++) {
      const int row = mt * 16 + kg * 4 + rr;
      int4* erow4 = (int4*)(e + (size_t)(blk + row) * HD);
      const int4 eo = erow4[c];
      const u32 eu[4] = {(u32)eo.x, (u32)eo.y, (u32)eo.z, (u32)eo.w};
      float mv[8];
      float wp = 0.f;
#pragma unroll
      for (int nt = 0; nt < 8; nt++) {
        mv[nt] = siluf(acc[mt][nt][rr] + bias2[nt]);
        wp += mv[nt] * swf[nt];
      }
      u32 mo[4], ou[4];
#pragma unroll
      for (int p = 0; p < 4; p++) {
        mo[p] = pk2(mv[2 * p], mv[2 * p + 1]);
        ou[p] = pk2(bf2f((u16)(eu[p] & 0xffffu)) + mv[2 * p],
                    bf2f((u16)(eu[p] >> 16)) + mv[2 * p + 1]);
      }
      ((int4*)(lMw + row * HD))[c ^ (row & 7)] =
          make_int4((int)mo[0], (int)mo[1], (int)mo[2], (int)mo[3]);
      erow4[c] = make_int4((int)ou[0], (int)ou[1], (int)ou[2], (int)ou[3]);
      wp += __shfl_xor(wp, 1);
      wp += __shfl_xor(wp, 2);
      wp += __shfl_xor(wp, 4);
      wp += __shfl_xor(wp, 8);
      wred[mt][rr] = wp;
    }
  }
#pragma unroll
  for (int mt = 0; mt < 2; mt++)
#pragma unroll
    for (int rr = 0; rr < 4; rr++)
      if (c == mt * 4 + rr) swgw[mt * 16 + kg * 4 + rr] = sigf(wred[mt][rr] + sbv);
  // swgw/lMw are wave-private; in-order DS pipe makes them visible to this wave

  // ---- msum run-aggregation (lane l owns slots l and l+64) ----
  const int gM = ((l >> 3) << 3);
  const int em = l & 7;
  float a0 = 0.f, a1 = 0.f;
  int cur = sdstw[0];
  for (int r = 0; r < 32; r++) {
    const int dn = sdstw[r];
    if (dn != cur) {  // wave-uniform branch: flush run
      atomicAdd(&msum[(size_t)cur * HD + l], a0);
      atomicAdd(&msum[(size_t)cur * HD + l + 64], a1);
      a0 = 0.f; a1 = 0.f; cur = dn;
    }
    const int rx = (r & 7) << 3;
    const float wgr = swgw[r];
    a0 += wgr * bf2f((u16)lMw[r * HD + (gM ^ rx) + em]);
    a1 += wgr * bf2f((u16)lMw[r * HD + (gM ^ rx) + 64 + em]);
  }
  atomicAdd(&msum[(size_t)cur * HD + l], a0);
  atomicAdd(&msum[(size_t)cur * HD + l + 64], a1);
}

// ---------------- node update layer: MT=2, fused residual, zeroes msum --------
__global__ __launch_bounds__(64, 4) void k_node(
    u16* __restrict__ feat, float* __restrict__ msum,
    const u16* __restrict__ Wtu1, const u16* __restrict__ Wtu2p,
    const void* __restrict__ b1g, const void* __restrict__ b2g,
    const int* __restrict__ flagp, int layer) {
  __shared__ __align__(16) short lA[32 * HD];
  const int mode = *flagp;
  const int l = threadIdx.x;
  const int c = l & 15, kg = l >> 4;
  short* lAw = lA;
  // XCD-chunked swizzle (grid = 1024 = 8 x 128), aligned with k_edge's chunks
  const int bid = (int)blockIdx.x;
  const int blkn = (((bid & 7) << 7) | (bid >> 3)) * 32;
  const u16* W1l = Wtu1 + (size_t)layer * PANEL;
  const u16* W2l = Wtu2p + (size_t)layer * PANEL;
  float bias1[8], bias2[8];
#pragma unroll
  for (int nt = 0; nt < 8; nt++) {
    bias1[nt] = ldinf(b1g, layer * HD + nt * 16 + c, mode);
    bias2[nt] = ldinf(b2g, layer * HD + nt * 16 + c, mode);
  }
  // stage upd_in = feat + msum, then zero msum for the next layer
  const float4 z4 = make_float4(0.f, 0.f, 0.f, 0.f);
#pragma unroll
  for (int rp = 0; rp < 8; rp++) {
    const int r = rp * 4 + (l >> 4);
    const int g = l & 15;
    const int4 fv = ((const int4*)(feat + (size_t)(blkn + r) * HD))[g];
    const u32 uu[4] = {(u32)fv.x, (u32)fv.y, (u32)fv.z, (u32)fv.w};
    float4* mrow4 = (float4*)(msum + (size_t)(blkn + r) * HD);
    const float4 ma = mrow4[2 * g];
    const float4 mb = mrow4[2 * g + 1];
    mrow4[2 * g] = z4;
    mrow4[2 * g + 1] = z4;
    const float mm[8] = {ma.x, ma.y, ma.z, ma.w, mb.x, mb.y, mb.z, mb.w};
    u32 ou[4];
#pragma unroll
    for (int p = 0; p < 4; p++) {
      ou[p] = pk2(bf2f((u16)(uu[p] & 0xffffu)) + mm[2 * p],
                  bf2f((u16)(uu[p] >> 16)) + mm[2 * p + 1]);
    }
    ((int4*)(lAw + r * HD))[g ^ (r & 7)] =
        make_int4((int)ou[0], (int)ou[1], (int)ou[2], (int)ou[3]);
  }
  __syncthreads();
  f32x4 acc[2][8];
  acc_zero<2>(acc);
  wave_gemm_p<2>(lAw, W1l, l, c, kg, acc);
  __syncthreads();
  wave_pack<2, true>(lAw, c, kg, acc, bias1);
  __syncthreads();
  acc_zero<2>(acc);
  wave_gemm_p<2>(lAw, W2l, l, c, kg, acc);

  // fused residual: feat[row] granule c += (acc + bias2), direct int4 RMW
#pragma unroll
  for (int mt = 0; mt < 2; mt++) {
#pragma unroll
    for (int rr = 0; rr < 4; rr++) {
      const int row = mt * 16 + kg * 4 + rr;
      int4* frow4 = (int4*)(feat + (size_t)(blkn + row) * HD);
      const int4 fo = frow4[c];
      const u32 fu[4] = {(u32)fo.x, (u32)fo.y, (u32)fo.z, (u32)fo.w};
      u32 ou[4];
#pragma unroll
      for (int p = 0; p < 4; p++) {
        const float x0 = acc[mt][2 * p][rr] + bias2[2 * p];
        const float x1 = acc[mt][2 * p + 1][rr] + bias2[2 * p + 1];
        ou[p] = pk2(bf2f((u16)(fu[p] & 0xffffu)) + x0,
                    bf2f((u16)(fu[p] >> 16)) + x1);
      }
      frow4[c] = make_int4((int)ou[0], (int)ou[1], (int)ou[2], (int)ou[3]);
    }
  }
}

// ---------------- output MLP + readout: MT=2 ----------------
__global__ __launch_bounds__(64, 4) void k_out(
    const u16* __restrict__ feat, const int* __restrict__ seg,
    const u16* __restrict__ Wto1, const u16* __restrict__ Wto2p,
    const void* __restrict__ ob1, const void* __restrict__ ob2,
    const int* __restrict__ flagp,
    float* __restrict__ sacc, u32* __restrict__ mxacc, float* __restrict__ cnt) {
  __shared__ __align__(16) short lA[32 * HD];
  __shared__ int sseg[32];
  const int mode = *flagp;
  const int l = threadIdx.x;
  const int c = l & 15, kg = l >> 4;
  short* lAw = lA;
  const int bid = (int)blockIdx.x;
  const int blkn = (((bid & 7) << 7) | (bid >> 3)) * 32;
  float bias1[8], bias2[8];
#pragma unroll
  for (int nt = 0; nt < 8; nt++) {
    bias1[nt] = ldinf(ob1, nt * 16 + c, mode);
    bias2[nt] = ldinf(ob2, nt * 16 + c, mode);
  }
#pragma unroll
  for (int rp = 0; rp < 8; rp++) {
    const int r = rp * 4 + (l >> 4);
    const int g = l & 15;
    ((int4*)(lAw + r * HD))[g ^ (r & 7)] =
        ((const int4*)(feat + (size_t)(blkn + r) * HD))[g];
  }
  if (l < 32) sseg[l] = seg[blkn + l];
  __syncthreads();
  f32x4 acc[2][8];
  acc_zero<2>(acc);
  wave_gemm_p<2>(lAw, Wto1, l, c, kg, acc);
  __syncthreads();
  wave_pack<2, true>(lAw, c, kg, acc, bias1);
  __syncthreads();
  acc_zero<2>(acc);
  wave_gemm_p<2>(lAw, Wto2p, l, c, kg, acc);
  __syncthreads();
  wave_pack<2, false>(lAw, c, kg, acc, bias2);
  __syncthreads();

  // lane l owns u32 position l (slots 2l, 2l+1); sacc/mxacc slot order
  const int gL = l >> 2;
  const int eoff = (l & 3) * 2;
  const bool uniform = (sseg[0] == sseg[31]);
  if (uniform) {
    const int g = sseg[0];
    float s1 = 0.f, s2 = 0.f, x1 = -3.402823e38f, x2 = -3.402823e38f;
#pragma unroll 4
    for (int r = 0; r < 32; r++) {
      const u32 mv = *(const u32*)&lAw[r * HD + ((gL ^ (r & 7)) << 3) + eoff];
      const float v1 = bf2f((u16)(mv & 0xffffu));
      const float v2 = bf2f((u16)(mv >> 16));
      s1 += v1; s2 += v2;
      x1 = fmaxf(x1, v1); x2 = fmaxf(x2, v2);
    }
    atomicAdd(&sacc[(size_t)g * HD + 2 * l], s1);
    atomicAdd(&sacc[(size_t)g * HD + 2 * l + 1], s2);
    atomicMax(&mxacc[(size_t)g * HD + 2 * l], ordu(x1));
    atomicMax(&mxacc[(size_t)g * HD + 2 * l + 1], ordu(x2));
    if (l == 0) atomicAdd(&cnt[g], 32.0f);
  } else {
    if (l < 32) atomicAdd(&cnt[sseg[l]], 1.0f);
#pragma unroll 4
    for (int r = 0; r < 32; r++) {
      const u32 mv = *(const u32*)&lAw[r * HD + ((gL ^ (r & 7)) << 3) + eoff];
      const float v1 = bf2f((u16)(mv & 0xffffu));
      const float v2 = bf2f((u16)(mv >> 16));
      const int g = sseg[r];
      atomicAdd(&sacc[(size_t)g * HD + 2 * l], v1);
      atomicAdd(&sacc[(size_t)g * HD + 2 * l + 1], v2);
      atomicMax(&mxacc[(size_t)g * HD + 2 * l], ordu(v1));
      atomicMax(&mxacc[(size_t)g * HD + 2 * l + 1], ordu(v2));
    }
  }
}

// ---------------- finalize: un-permute slot order -> h order ------------------
__global__ __launch_bounds__(256) void k_final(const float* __restrict__ sacc,
                                               const u32* __restrict__ mxacc,
                                               const float* __restrict__ cnt,
                                               const int* __restrict__ flagp,
                                               void* __restrict__ out) {
  const int mode = *flagp;
  const int i = blockIdx.x * 256 + threadIdx.x;
  const int b = i / 384, j = i % 384;
  float v;
  if (j < HD) {
    const int p = ((j & 15) << 3) | (j >> 4);
    v = sacc[b * HD + p];
  } else if (j < 2 * HD) {
    const int t = j - HD;
    const int p = ((t & 15) << 3) | (t >> 4);
    v = sacc[b * HD + p] / fmaxf(cnt[b], 1.0f);
  } else {
    const int t = j - 2 * HD;
    const int p = ((t & 15) << 3) | (t >> 4);
    u32 u = mxacc[b * HD + p];
    u32 bits = (u >> 31) ? (u ^ 0x80000000u) : ~u;
    v = __uint_as_float(bits);
  }
  if (mode) ((float*)out)[i] = v;
  else ((u16*)out)[i] = f2bf(v);
}

extern "C" void kernel_launch(void* const* d_in, const int* in_sizes, int n_in,
                              void* d_out, int out_size, void* d_ws, size_t ws_size,
                              hipStream_t stream) {
  const void* d_d = d_in[0];
  const int* src = (const int*)d_in[1];
  const int* dst = (const int*)d_in[2];
  const int* seg = (const int*)d_in[3];
  const void* nemb = d_in[4];
  const void* We = d_in[5];
  const void* be = d_in[6];
  const void* mW1 = d_in[7];
  const void* mb1 = d_in[8];
  const void* mW2 = d_in[9];
  const void* mb2 = d_in[10];
  const void* sW = d_in[11];
  const void* sb = d_in[12];
  const void* uW1 = d_in[13];
  const void* ub1 = d_in[14];
  const void* uW2 = d_in[15];
  const void* ub2 = d_in[16];
  const void* oW1 = d_in[17];
  const void* ob1 = d_in[18];
  const void* oW2 = d_in[19];
  const void* ob2 = d_in[20];

  char* ws = (char*)d_ws;
  const size_t OFF_E = 0;
  const size_t OFF_MSUM = OFF_E + (size_t)NE * HD * 2;
  const size_t OFF_FEAT = OFF_MSUM + (size_t)NN * HD * 4;
  const size_t OFF_SACC = OFF_FEAT + (size_t)NN * HD * 2;
  const size_t OFF_MX = OFF_SACC + (size_t)NB * HD * 4;
  const size_t OFF_CNT = OFF_MX + (size_t)NB * HD * 4;
  const size_t OFF_DEG = OFF_CNT + 1024;
  const size_t OFF_ROWPTR = OFF_DEG + (size_t)NN * 4;
  const size_t OFF_CURSOR = OFF_ROWPTR + (size_t)(NN + 2) * 4;
  const size_t OFF_EIDS = OFF_CURSOR + (size_t)NN * 4;
  const size_t OFF_SRCS = OFF_EIDS + (size_t)NE * 4;
  const size_t OFF_DSTS = OFF_SRCS + (size_t)NE * 4;
  const size_t OFF_WT1 = OFF_DSTS + (size_t)NE * 4;
  const size_t OFF_WT2P = OFF_WT1 + (size_t)NL * 3 * PANEL * 2;
  const size_t OFF_WTU1 = OFF_WT2P + (size_t)NL * PANEL * 2;
  const size_t OFF_WTU2P = OFF_WTU1 + (size_t)NL * PANEL * 2;
  const size_t OFF_WTO1 = OFF_WTU2P + (size_t)NL * PANEL * 2;
  const size_t OFF_WTO2P = OFF_WTO1 + (size_t)PANEL * 2;
  const size_t OFF_FLAG = OFF_WTO2P + (size_t)PANEL * 2;

  u16* e = (u16*)(ws + OFF_E);
  float* msum = (float*)(ws + OFF_MSUM);
  u16* feat = (u16*)(ws + OFF_FEAT);
  float* sacc = (float*)(ws + OFF_SACC);
  u32* mx = (u32*)(ws + OFF_MX);
  float* cnt = (float*)(ws + OFF_CNT);
  u32* deg = (u32*)(ws + OFF_DEG);
  int* rowptr = (int*)(ws + OFF_ROWPTR);
  int* cursor = (int*)(ws + OFF_CURSOR);
  int* eids = (int*)(ws + OFF_EIDS);
  int* src_s = (int*)(ws + OFF_SRCS);
  int* dst_s = (int*)(ws + OFF_DSTS);
  u16* Wt1 = (u16*)(ws + OFF_WT1);
  u16* Wt2p = (u16*)(ws + OFF_WT2P);
  u16* Wtu1 = (u16*)(ws + OFF_WTU1);
  u16* Wtu2p = (u16*)(ws + OFF_WTU2P);
  u16* Wto1 = (u16*)(ws + OFF_WTO1);
  u16* Wto2p = (u16*)(ws + OFF_WTO2P);
  int* flag = (int*)(ws + OFF_FLAG);

  // zero sacc + mx + cnt + deg (contiguous region)
  hipMemsetAsync(ws + OFF_SACC, 0,
                 (size_t)NB * HD * 4 * 2 + 1024 + (size_t)NN * 4, stream);
  // zero msum once (layer 0); k_node re-zeroes it for subsequent layers
  hipMemsetAsync(msum, 0, (size_t)NN * HD * 4, stream);

  k_detect<<<1, 64, 0, stream>>>((const u16*)We, flag);
  k_prep<<<256, 256, 0, stream>>>(mW1, mW2, uW1, uW2, oW1, oW2, flag,
                                  Wt1, Wt2p, Wtu1, Wtu2p, Wto1, Wto2p);
  k_featinit<<<(NN * HD / 8) / 256, 256, 0, stream>>>(nemb, flag, feat);

  // CSR by dst (sorted edge order used everywhere)
  k_csr_deg<<<NE / 256, 256, 0, stream>>>(dst, deg);
  k_csr_scan<<<1, 1024, 0, stream>>>(deg, rowptr, cursor);
  k_csr_scatter<<<NE / 256, 256, 0, stream>>>(dst, src, cursor, eids, src_s, dst_s);

  k_encode<<<NE / 256, 256, 0, stream>>>(d_d, eids, We, be, flag, e);

  for (int l = 0; l < NL; l++) {
    k_edge<<<NE / 128, 256, 0, stream>>>(feat, e, src_s, dst_s, Wt1, Wt2p,
                                         mb1, mb2, sW, sb, flag, msum, l);
    k_node<<<NN / 32, 64, 0, stream>>>(feat, msum, Wtu1, Wtu2p, ub1, ub2, flag, l);
  }
  k_out<<<NN / 32, 64, 0, stream>>>(feat, seg, Wto1, Wto2p, ob1, ob2, flag, sacc, mx, cnt);
  k_final<<<(NB * 384) / 256, 256, 0, stream>>>(sacc, mx, cnt, flag, d_out);
}

// Round 15
// 717.920 us; speedup vs baseline: 1.1282x; 1.0329x over previous
//
#include <hip/hip_runtime.h>
#include <hip/hip_bf16.h>

#define NN 32768   // nodes
#define NB 256     // graphs
#define HD 128     // hidden
#define NL 4       // layers
#define NE 262144  // edges

typedef short bf16x8 __attribute__((ext_vector_type(8)));
typedef float f32x4 __attribute__((ext_vector_type(4)));
typedef unsigned short u16;
typedef unsigned int u32;

__device__ __forceinline__ float bf2f(u16 u) {
  return __uint_as_float(((u32)u) << 16);
}
__device__ __forceinline__ u16 f2bf(float f) {
  u32 x = __float_as_uint(f);
  u32 r = x + 0x7FFFu + ((x >> 16) & 1u);
  return (u16)(r >> 16);
}
__device__ __forceinline__ u32 pk2(float a, float b) {
  __hip_bfloat162 h = __float22bfloat162_rn(make_float2(a, b));
  return *reinterpret_cast<u32*>(&h);
}
__device__ __forceinline__ float siluf(float x) {
  return x * __builtin_amdgcn_rcpf(1.0f + __expf(-x));
}
__device__ __forceinline__ float sigf(float x) {
  return __builtin_amdgcn_rcpf(1.0f + __expf(-x));
}
__device__ __forceinline__ u32 ordu(float f) {
  u32 b = __float_as_uint(f);
  return (b & 0x80000000u) ? ~b : (b | 0x80000000u);
}

// ---- adaptive input loads: mode 1 = f32 inputs, mode 0 = bf16 inputs ----
__device__ __forceinline__ float ldinf(const void* p, size_t i, int mode) {
  return mode ? ((const float*)p)[i] : bf2f(((const u16*)p)[i]);
}
__device__ __forceinline__ u16 ldinb(const void* p, size_t i, int mode) {
  return mode ? f2bf(((const float*)p)[i]) : ((const u16*)p)[i];
}

// ---- dtype detector ----
__global__ void k_detect(const u16* __restrict__ Weraw, int* __restrict__ flag) {
  if (threadIdx.x == 0 && blockIdx.x == 0) {
    int cnt = 0;
    for (int i = 0; i < 256; i++) {
      u16 u = Weraw[2 * i];
      u32 e = (u >> 7) & 0xFFu;
      if (e >= 112u && e <= 126u) cnt++;
    }
    *flag = (cnt >= 128) ? 0 : 1;
  }
}

// ---- layer-0 bias fold: v0[n] = nemb @ (W1[0:128,n] + W1[128:256,n]) ----
__global__ void k_v0(const void* __restrict__ nemb, const void* __restrict__ mW1,
                     const int* __restrict__ flagp, float* __restrict__ v0f) {
  const int mode = *flagp;
  const int n = threadIdx.x;  // 128
  float s = 0.f;
  for (int k = 0; k < 256; k++)
    s += ldinf(nemb, k & 127, mode) * ldinf(mW1, (size_t)k * HD + n, mode);
  v0f[n] = s;
}

// ================= SLOT ORDER / SORTED EDGES / XCD CHUNKING =================
// (see prior rounds) slot s <-> h=(s&7)*16+(s>>3); weight panels fold perm;
// edge arrays dst-sorted; block ids chunk-swizzled per XCD.
#define PANEL 16384  // shorts per packed 128x128 weight panel

// ---------------- CSR build (by dst) ----------------
__global__ __launch_bounds__(256) void k_csr_deg(const int* __restrict__ dstp,
                                                 u32* __restrict__ deg) {
  const int i = blockIdx.x * 256 + threadIdx.x;
  atomicAdd(&deg[dstp[i]], 1u);
}

__global__ __launch_bounds__(1024) void k_csr_scan(const u32* __restrict__ deg,
                                                   int* __restrict__ rowptr,
                                                   int* __restrict__ cursor) {
  __shared__ int part[1024];
  const int t = threadIdx.x;
  int loc[32];
  int s = 0;
#pragma unroll
  for (int j = 0; j < 32; j++) { loc[j] = s; s += (int)deg[t * 32 + j]; }
  part[t] = s;
  __syncthreads();
  int inc = s;
  for (int off = 1; off < 1024; off <<= 1) {
    int tmp = (t >= off) ? part[t - off] : 0;
    __syncthreads();
    part[t] += tmp;
    __syncthreads();
  }
  const int base = part[t] - inc;
#pragma unroll
  for (int j = 0; j < 32; j++) {
    rowptr[t * 32 + j] = base + loc[j];
    cursor[t * 32 + j] = base + loc[j];
  }
  if (t == 1023) rowptr[NN] = part[1023];
}

__global__ __launch_bounds__(256) void k_csr_scatter(const int* __restrict__ dstp,
                                                     const int* __restrict__ srcp,
                                                     int* __restrict__ cursor,
                                                     int* __restrict__ eids,
                                                     int* __restrict__ src_s,
                                                     int* __restrict__ dst_s) {
  const int i = blockIdx.x * 256 + threadIdx.x;
  const int d = dstp[i];
  const int pos = atomicAdd(&cursor[d], 1);
  eids[pos] = i;
  src_s[pos] = srcp[i];
  dst_s[pos] = d;
}

// ---------------- per-wave GEMM pieces ----------------
template <int MT>
__device__ __forceinline__ void acc_zero(f32x4 (&acc)[MT][8]) {
#pragma unroll
  for (int mt = 0; mt < MT; mt++)
#pragma unroll
    for (int nt = 0; nt < 8; nt++) acc[mt][nt] = f32x4{0.f, 0.f, 0.f, 0.f};
}

__device__ __forceinline__ void load_a2(const u16* __restrict__ A0,
                                        const size_t* rowoff, int kg,
                                        bf16x8 (&a)[2][4]) {
#pragma unroll
  for (int ks = 0; ks < 4; ks++)
#pragma unroll
    for (int mt = 0; mt < 2; mt++)
      a[mt][ks] = *(const bf16x8*)&A0[rowoff[mt] + ks * 32 + kg * 8];
}

__device__ __forceinline__ void gemm_lds2(const bf16x8 (&a)[2][4],
                                          const short* sB, int l,
                                          f32x4 (&acc)[2][8]) {
#pragma unroll
  for (int ks = 0; ks < 4; ks++)
#pragma unroll
    for (int nt = 0; nt < 8; nt++) {
      bf16x8 b = *(const bf16x8*)&sB[((nt * 4 + ks) * 64 + l) * 8];
#pragma unroll
      for (int mt = 0; mt < 2; mt++)
        acc[mt][nt] = __builtin_amdgcn_mfma_f32_16x16x32_bf16(a[mt][ks], b, acc[mt][nt], 0, 0, 0);
    }
}

template <int MT>
__device__ __forceinline__ void wave_gemm_p(const short* lAw, const u16* __restrict__ Bp,
                                            int l, int c, int kg, f32x4 (&acc)[MT][8]) {
#pragma unroll
  for (int ks = 0; ks < 4; ks++) {
    bf16x8 a[MT];
#pragma unroll
    for (int mt = 0; mt < MT; mt++) {
      const int r = mt * 16 + c;
      const int k = ks * 32 + kg * 8;
      a[mt] = *(const bf16x8*)&lAw[r * HD + (k ^ ((r & 7) << 3))];
    }
#pragma unroll
    for (int nt = 0; nt < 8; nt++) {
      bf16x8 b = *(const bf16x8*)&Bp[(size_t)((nt * 4 + ks) * 64 + l) * 8];
#pragma unroll
      for (int mt = 0; mt < MT; mt++)
        acc[mt][nt] = __builtin_amdgcn_mfma_f32_16x16x32_bf16(a[mt], b, acc[mt][nt], 0, 0, 0);
    }
  }
}

template <int MT, bool SILU>
__device__ __forceinline__ void wave_pack(short* lAw, int c, int kg,
                                          f32x4 (&acc)[MT][8], const float* bias) {
#pragma unroll
  for (int mt = 0; mt < MT; mt++) {
#pragma unroll
    for (int rr = 0; rr < 4; rr++) {
      const int row = mt * 16 + kg * 4 + rr;
      u32 ou[4];
#pragma unroll
      for (int p = 0; p < 4; p++) {
        float x0 = acc[mt][2 * p][rr] + bias[2 * p];
        float x1 = acc[mt][2 * p + 1][rr] + bias[2 * p + 1];
        if (SILU) { x0 = siluf(x0); x1 = siluf(x1); }
        ou[p] = pk2(x0, x1);
      }
      ((int4*)(lAw + row * HD))[c ^ (row & 7)] =
          make_int4((int)ou[0], (int)ou[1], (int)ou[2], (int)ou[3]);
    }
  }
}

__device__ __forceinline__ void stage_panel(const u16* __restrict__ P,
                                            short* sB, int tid) {
#pragma unroll
  for (int it = 0; it < 8; it++) {
    const int idx = (it * 256 + tid) * 8;
    *(int4*)&sB[idx] = *(const int4*)&P[idx];
  }
}

// ---------------- weight prep: pack panels, fold slot permutation -------------
__global__ __launch_bounds__(256) void k_prep(
    const void* __restrict__ mW1, const void* __restrict__ mW2,
    const void* __restrict__ uW1, const void* __restrict__ uW2,
    const void* __restrict__ oW1, const void* __restrict__ oW2,
    const int* __restrict__ flagp,
    u16* __restrict__ Wt1, u16* __restrict__ Wt2p,
    u16* __restrict__ Wtu1, u16* __restrict__ Wtu2p,
    u16* __restrict__ Wto1, u16* __restrict__ Wto2p) {
  const int mode = *flagp;
  const int tid = blockIdx.x * blockDim.x + threadIdx.x;
  const int stride = gridDim.x * blockDim.x;
  for (int i = tid; i < NL * 3 * PANEL; i += stride) {
    const int l = i / (3 * PANEL), r = i % (3 * PANEL);
    const int chunk = r / PANEL, r2 = r % PANEL;
    const int nt = r2 / 2048, ks = (r2 % 2048) / 512;
    const int lane = (r2 % 512) / 8, j = r2 % 8;
    const int s = ks * 32 + (lane >> 4) * 8 + j;
    const int klog = ((s & 7) << 4) | (s >> 3);
    const int n = nt * 16 + (lane & 15);
    Wt1[i] = ldinb(mW1, ((size_t)l * 384 + chunk * 128 + klog) * HD + n, mode);
  }
  for (int i = tid; i < NL * PANEL; i += stride) {
    const int l = i / PANEL, r = i % PANEL;
    const int nt = r / 2048, ks = (r % 2048) / 512;
    const int lane = (r % 512) / 8, j = r % 8;
    const int s = ks * 32 + (lane >> 4) * 8 + j;
    const int klog = ((s & 7) << 4) | (s >> 3);
    const int n = nt * 16 + (lane & 15);
    Wt2p[i] = ldinb(mW2, ((size_t)l * HD + klog) * HD + n, mode);
    Wtu1[i] = ldinb(uW1, ((size_t)l * HD + klog) * HD + n, mode);
    Wtu2p[i] = ldinb(uW2, ((size_t)l * HD + klog) * HD + n, mode);
  }
  for (int i = tid; i < PANEL; i += stride) {
    const int nt = i / 2048, ks = (i % 2048) / 512;
    const int lane = (i % 512) / 8, j = i % 8;
    const int s = ks * 32 + (lane >> 4) * 8 + j;
    const int klog = ((s & 7) << 4) | (s >> 3);
    const int n = nt * 16 + (lane & 15);
    Wto1[i] = ldinb(oW1, (size_t)klog * HD + n, mode);
    Wto2p[i] = ldinb(oW2, (size_t)klog * HD + n, mode);
  }
}

// ---------------- feat init (slot order) ----------------
__global__ __launch_bounds__(256) void k_featinit(const void* __restrict__ nemb,
                                                  const int* __restrict__ flagp,
                                                  u16* __restrict__ feat) {
  const int mode = *flagp;
  const int i = blockIdx.x * 256 + threadIdx.x;
  const int g = i & 15;
  u32 ou[4];
#pragma unroll
  for (int p = 0; p < 4; p++) {
    u16 a = ldinb(nemb, (2 * p) * 16 + g, mode);
    u16 b = ldinb(nemb, (2 * p + 1) * 16 + g, mode);
    ou[p] = (u32)a | ((u32)b << 16);
  }
  ((int4*)feat)[i] = make_int4((int)ou[0], (int)ou[1], (int)ou[2], (int)ou[3]);
}

// ---------------- edge feature encode (sorted order, slot order) --------------
__global__ __launch_bounds__(256) void k_encode(const void* __restrict__ d,
                                                const int* __restrict__ eids,
                                                const void* __restrict__ We,
                                                const void* __restrict__ be,
                                                const int* __restrict__ flagp,
                                                u16* __restrict__ e) {
  const int mode = *flagp;
  __shared__ float sW[9 * HD];
  __shared__ float sb[HD];
  for (int i = threadIdx.x; i < 9 * HD; i += 256) sW[i] = ldinf(We, i, mode);
  for (int i = threadIdx.x; i < HD; i += 256) sb[i] = ldinf(be, i, mode);
  __syncthreads();
  const int spos = blockIdx.x * 256 + threadIdx.x;
  const float dv = ldinf(d, eids[spos], mode);
  float de[9];
#pragma unroll
  for (int k = 0; k < 4; k++) {
    float x = dv * (1.0f / (float)(1 << k));
    de[k] = __sinf(x);
    de[4 + k] = __cosf(x);
  }
  de[8] = dv;
  u16* erow = e + (size_t)spos * HD;
#pragma unroll
  for (int g = 0; g < 16; g++) {
    u32 ou[4];
#pragma unroll
    for (int p = 0; p < 4; p++) {
      float vv[2];
#pragma unroll
      for (int t = 0; t < 2; t++) {
        const int h = (2 * p + t) * 16 + g;
        float a = sb[h];
#pragma unroll
        for (int k = 0; k < 9; k++) a += de[k] * sW[k * HD + h];
        vv[t] = siluf(siluf(a));
      }
      ou[p] = pk2(vv[0], vv[1]);
    }
    ((int4*)erow)[g] = make_int4((int)ou[0], (int)ou[1], (int)ou[2], (int)ou[3]);
  }
}

// ---------------- edge message layer: 4-wave blocks, B in LDS -----------------
// FIRST (layer 0): feat[src]=feat[dst]=nemb for all edges, so those two
// K-chunks fold into bias via v0f; single-chunk GEMM1 (e), no gathers.
template <bool FIRST>
__global__ __launch_bounds__(256, 2) void k_edge(
    const u16* __restrict__ feat, u16* __restrict__ e,
    const int* __restrict__ src_s, const int* __restrict__ dst_s,
    const u16* __restrict__ Wt1, const u16* __restrict__ Wt2p,
    const void* __restrict__ b1g, const void* __restrict__ b2g,
    const void* __restrict__ softW, const void* __restrict__ softb,
    const int* __restrict__ flagp, const float* __restrict__ v0f,
    float* __restrict__ msum, int layer) {
  __shared__ __align__(16) short sB[PANEL];
  __shared__ __align__(16) short lM[128 * HD];
  __shared__ float swg[128];
  __shared__ int sdst[128];
  const int mode = *flagp;
  const int tid = threadIdx.x;
  const int l = tid & 63, wid = tid >> 6;
  const int c = l & 15, kg = l >> 4;
  const int bid = (int)blockIdx.x;
  const int blkB = (((bid & 7) << 8) | (bid >> 3)) * 128;
  const int blk = blkB + wid * 32;
  short* lMw = lM + wid * 32 * HD;
  float* swgw = swg + wid * 32;
  int* sdstw = sdst + wid * 32;

  if (l < 32) sdstw[l] = dst_s[blk + l];

  size_t offS[2], offD[2], offE[2];
#pragma unroll
  for (int mt = 0; mt < 2; mt++) {
    const int eidx = blk + mt * 16 + c;
    if (!FIRST) {
      offS[mt] = (size_t)src_s[eidx] * HD;
      offD[mt] = (size_t)dst_s[eidx] * HD;
    }
    offE[mt] = (size_t)eidx * HD;
  }

  const u16* W1l = Wt1 + (size_t)layer * 3 * PANEL;
  const u16* W2l = Wt2p + (size_t)layer * PANEL;
  float bias1[8], bias2[8], swf[8];
#pragma unroll
  for (int nt = 0; nt < 8; nt++) {
    bias1[nt] = ldinf(b1g, layer * HD + nt * 16 + c, mode);
    if (FIRST) bias1[nt] += v0f[nt * 16 + c];
    bias2[nt] = ldinf(b2g, layer * HD + nt * 16 + c, mode);
    swf[nt] = ldinf(softW, (size_t)layer * HD + nt * 16 + c, mode);
  }
  const float sbv = ldinf(softb, layer, mode);

  f32x4 acc[2][8];
  acc_zero<2>(acc);
  bf16x8 a[2][4];

  if (!FIRST) {
    load_a2(feat, offS, kg, a);
    stage_panel(W1l, sB, tid);
    __syncthreads();
    gemm_lds2(a, sB, l, acc);
    __syncthreads();
    load_a2(feat, offD, kg, a);
    stage_panel(W1l + PANEL, sB, tid);
    __syncthreads();
    gemm_lds2(a, sB, l, acc);
    __syncthreads();
  }
  load_a2(e, offE, kg, a);
  stage_panel(W1l + 2 * PANEL, sB, tid);
  __syncthreads();
  gemm_lds2(a, sB, l, acc);
  __syncthreads();

  // stage W2 while packing h1 into own lM slice
  stage_panel(W2l, sB, tid);
  wave_pack<2, true>(lMw, c, kg, acc, bias1);
  __syncthreads();

  acc_zero<2>(acc);
  wave_gemm_p<2>(lMw, (const u16*)sB, l, c, kg, acc);

  // ---- fused: pack m -> lMw, gate, e += m ----
  float wred[2][4];
#pragma unroll
  for (int mt = 0; mt < 2; mt++) {
#pragma unroll
    for (int rr = 0; rr < 4; rr++) {
      const int row = mt * 16 + kg * 4 + rr;
      int4* erow4 = (int4*)(e + (size_t)(blk + row) * HD);
      const int4 eo = erow4[c];
      const u32 eu[4] = {(u32)eo.x, (u32)eo.y, (u32)eo.z, (u32)eo.w};
      float mv[8];
      float wp = 0.f;
#pragma unroll
      for (int nt = 0; nt < 8; nt++) {
        mv[nt] = siluf(acc[mt][nt][rr] + bias2[nt]);
        wp += mv[nt] * swf[nt];
      }
      u32 mo[4], ou[4];
#pragma unroll
      for (int p = 0; p < 4; p++) {
        mo[p] = pk2(mv[2 * p], mv[2 * p + 1]);
        ou[p] = pk2(bf2f((u16)(eu[p] & 0xffffu)) + mv[2 * p],
                    bf2f((u16)(eu[p] >> 16)) + mv[2 * p + 1]);
      }
      ((int4*)(lMw + row * HD))[c ^ (row & 7)] =
          make_int4((int)mo[0], (int)mo[1], (int)mo[2], (int)mo[3]);
      erow4[c] = make_int4((int)ou[0], (int)ou[1], (int)ou[2], (int)ou[3]);
      wp += __shfl_xor(wp, 1);
      wp += __shfl_xor(wp, 2);
      wp += __shfl_xor(wp, 4);
      wp += __shfl_xor(wp, 8);
      wred[mt][rr] = wp;
    }
  }
#pragma unroll
  for (int mt = 0; mt < 2; mt++)
#pragma unroll
    for (int rr = 0; rr < 4; rr++)
      if (c == mt * 4 + rr) swgw[mt * 16 + kg * 4 + rr] = sigf(wred[mt][rr] + sbv);

  // ---- msum run-aggregation ----
  const int gM = ((l >> 3) << 3);
  const int em = l & 7;
  float a0 = 0.f, a1 = 0.f;
  int cur = sdstw[0];
  for (int r = 0; r < 32; r++) {
    const int dn = sdstw[r];
    if (dn != cur) {
      atomicAdd(&msum[(size_t)cur * HD + l], a0);
      atomicAdd(&msum[(size_t)cur * HD + l + 64], a1);
      a0 = 0.f; a1 = 0.f; cur = dn;
    }
    const int rx = (r & 7) << 3;
    const float wgr = swgw[r];
    a0 += wgr * bf2f((u16)lMw[r * HD + (gM ^ rx) + em]);
    a1 += wgr * bf2f((u16)lMw[r * HD + (gM ^ rx) + 64 + em]);
  }
  atomicAdd(&msum[(size_t)cur * HD + l], a0);
  atomicAdd(&msum[(size_t)cur * HD + l + 64], a1);
}

// ---------------- node update; LAST also runs the out-MLP + readout -----------
template <bool LAST>
__global__ __launch_bounds__(64, 4) void k_node(
    u16* __restrict__ feat, float* __restrict__ msum,
    const u16* __restrict__ Wtu1, const u16* __restrict__ Wtu2p,
    const void* __restrict__ b1g, const void* __restrict__ b2g,
    const int* __restrict__ flagp, int layer,
    const int* __restrict__ seg,
    const u16* __restrict__ Wto1, const u16* __restrict__ Wto2p,
    const void* __restrict__ ob1, const void* __restrict__ ob2,
    float* __restrict__ sacc, u32* __restrict__ mxacc, float* __restrict__ cnt) {
  __shared__ __align__(16) short lA[32 * HD];
  __shared__ int sseg[32];
  const int mode = *flagp;
  const int l = threadIdx.x;
  const int c = l & 15, kg = l >> 4;
  short* lAw = lA;
  const int bid = (int)blockIdx.x;
  const int blkn = (((bid & 7) << 7) | (bid >> 3)) * 32;
  const u16* W1l = Wtu1 + (size_t)layer * PANEL;
  const u16* W2l = Wtu2p + (size_t)layer * PANEL;
  float bias1[8], bias2[8];
#pragma unroll
  for (int nt = 0; nt < 8; nt++) {
    bias1[nt] = ldinf(b1g, layer * HD + nt * 16 + c, mode);
    bias2[nt] = ldinf(b2g, layer * HD + nt * 16 + c, mode);
  }
  if (LAST && l < 32) sseg[l] = seg[blkn + l];

  // stage upd_in = feat + msum, then zero msum
  const float4 z4 = make_float4(0.f, 0.f, 0.f, 0.f);
#pragma unroll
  for (int rp = 0; rp < 8; rp++) {
    const int r = rp * 4 + (l >> 4);
    const int g = l & 15;
    const int4 fv = ((const int4*)(feat + (size_t)(blkn + r) * HD))[g];
    const u32 uu[4] = {(u32)fv.x, (u32)fv.y, (u32)fv.z, (u32)fv.w};
    float4* mrow4 = (float4*)(msum + (size_t)(blkn + r) * HD);
    const float4 ma = mrow4[2 * g];
    const float4 mb = mrow4[2 * g + 1];
    mrow4[2 * g] = z4;
    mrow4[2 * g + 1] = z4;
    const float mm[8] = {ma.x, ma.y, ma.z, ma.w, mb.x, mb.y, mb.z, mb.w};
    u32 ou[4];
#pragma unroll
    for (int p = 0; p < 4; p++) {
      ou[p] = pk2(bf2f((u16)(uu[p] & 0xffffu)) + mm[2 * p],
                  bf2f((u16)(uu[p] >> 16)) + mm[2 * p + 1]);
    }
    ((int4*)(lAw + r * HD))[g ^ (r & 7)] =
        make_int4((int)ou[0], (int)ou[1], (int)ou[2], (int)ou[3]);
  }
  __syncthreads();
  f32x4 acc[2][8];
  acc_zero<2>(acc);
  wave_gemm_p<2>(lAw, W1l, l, c, kg, acc);
  __syncthreads();
  wave_pack<2, true>(lAw, c, kg, acc, bias1);
  __syncthreads();
  acc_zero<2>(acc);
  wave_gemm_p<2>(lAw, W2l, l, c, kg, acc);
  __syncthreads();

  // residual: newfeat = feat + (acc + bias2)
  //   non-LAST: write to global feat;  LAST: write into lAw for the out-MLP
#pragma unroll
  for (int mt = 0; mt < 2; mt++) {
#pragma unroll
    for (int rr = 0; rr < 4; rr++) {
      const int row = mt * 16 + kg * 4 + rr;
      int4* frow4 = (int4*)(feat + (size_t)(blkn + row) * HD);
      const int4 fo = frow4[c];
      const u32 fu[4] = {(u32)fo.x, (u32)fo.y, (u32)fo.z, (u32)fo.w};
      u32 ou[4];
#pragma unroll
      for (int p = 0; p < 4; p++) {
        const float x0 = acc[mt][2 * p][rr] + bias2[2 * p];
        const float x1 = acc[mt][2 * p + 1][rr] + bias2[2 * p + 1];
        ou[p] = pk2(bf2f((u16)(fu[p] & 0xffffu)) + x0,
                    bf2f((u16)(fu[p] >> 16)) + x1);
      }
      const int4 nv = make_int4((int)ou[0], (int)ou[1], (int)ou[2], (int)ou[3]);
      if (LAST) {
        ((int4*)(lAw + row * HD))[c ^ (row & 7)] = nv;
      } else {
        frow4[c] = nv;
      }
    }
  }

  if (LAST) {
    __syncthreads();
    float ob1r[8], ob2r[8];
#pragma unroll
    for (int nt = 0; nt < 8; nt++) {
      ob1r[nt] = ldinf(ob1, nt * 16 + c, mode);
      ob2r[nt] = ldinf(ob2, nt * 16 + c, mode);
    }
    acc_zero<2>(acc);
    wave_gemm_p<2>(lAw, Wto1, l, c, kg, acc);
    __syncthreads();
    wave_pack<2, true>(lAw, c, kg, acc, ob1r);
    __syncthreads();
    acc_zero<2>(acc);
    wave_gemm_p<2>(lAw, Wto2p, l, c, kg, acc);
    __syncthreads();
    wave_pack<2, false>(lAw, c, kg, acc, ob2r);
    __syncthreads();

    // readout: lane l owns u32 slot position l (slots 2l, 2l+1)
    const int gL = l >> 2;
    const int eoff = (l & 3) * 2;
    const bool uniform = (sseg[0] == sseg[31]);
    if (uniform) {
      const int g = sseg[0];
      float s1 = 0.f, s2 = 0.f, x1 = -3.402823e38f, x2 = -3.402823e38f;
#pragma unroll 4
      for (int r = 0; r < 32; r++) {
        const u32 mv = *(const u32*)&lAw[r * HD + ((gL ^ (r & 7)) << 3) + eoff];
        const float v1 = bf2f((u16)(mv & 0xffffu));
        const float v2 = bf2f((u16)(mv >> 16));
        s1 += v1; s2 += v2;
        x1 = fmaxf(x1, v1); x2 = fmaxf(x2, v2);
      }
      atomicAdd(&sacc[(size_t)g * HD + 2 * l], s1);
      atomicAdd(&sacc[(size_t)g * HD + 2 * l + 1], s2);
      atomicMax(&mxacc[(size_t)g * HD + 2 * l], ordu(x1));
      atomicMax(&mxacc[(size_t)g * HD + 2 * l + 1], ordu(x2));
      if (l == 0) atomicAdd(&cnt[g], 32.0f);
    } else {
      if (l < 32) atomicAdd(&cnt[sseg[l]], 1.0f);
#pragma unroll 4
      for (int r = 0; r < 32; r++) {
        const u32 mv = *(const u32*)&lAw[r * HD + ((gL ^ (r & 7)) << 3) + eoff];
        const float v1 = bf2f((u16)(mv & 0xffffu));
        const float v2 = bf2f((u16)(mv >> 16));
        const int g = sseg[r];
        atomicAdd(&sacc[(size_t)g * HD + 2 * l], v1);
        atomicAdd(&sacc[(size_t)g * HD + 2 * l + 1], v2);
        atomicMax(&mxacc[(size_t)g * HD + 2 * l], ordu(v1));
        atomicMax(&mxacc[(size_t)g * HD + 2 * l + 1], ordu(v2));
      }
    }
  }
}

// ---------------- finalize: un-permute slot order -> h order ------------------
__global__ __launch_bounds__(256) void k_final(const float* __restrict__ sacc,
                                               const u32* __restrict__ mxacc,
                                               const float* __restrict__ cnt,
                                               const int* __restrict__ flagp,
                                               void* __restrict__ out) {
  const int mode = *flagp;
  const int i = blockIdx.x * 256 + threadIdx.x;
  const int b = i / 384, j = i % 384;
  float v;
  if (j < HD) {
    const int p = ((j & 15) << 3) | (j >> 4);
    v = sacc[b * HD + p];
  } else if (j < 2 * HD) {
    const int t = j - HD;
    const int p = ((t & 15) << 3) | (t >> 4);
    v = sacc[b * HD + p] / fmaxf(cnt[b], 1.0f);
  } else {
    const int t = j - 2 * HD;
    const int p = ((t & 15) << 3) | (t >> 4);
    u32 u = mxacc[b * HD + p];
    u32 bits = (u >> 31) ? (u ^ 0x80000000u) : ~u;
    v = __uint_as_float(bits);
  }
  if (mode) ((float*)out)[i] = v;
  else ((u16*)out)[i] = f2bf(v);
}

extern "C" void kernel_launch(void* const* d_in, const int* in_sizes, int n_in,
                              void* d_out, int out_size, void* d_ws, size_t ws_size,
                              hipStream_t stream) {
  const void* d_d = d_in[0];
  const int* src = (const int*)d_in[1];
  const int* dst = (const int*)d_in[2];
  const int* seg = (const int*)d_in[3];
  const void* nemb = d_in[4];
  const void* We = d_in[5];
  const void* be = d_in[6];
  const void* mW1 = d_in[7];
  const void* mb1 = d_in[8];
  const void* mW2 = d_in[9];
  const void* mb2 = d_in[10];
  const void* sW = d_in[11];
  const void* sb = d_in[12];
  const void* uW1 = d_in[13];
  const void* ub1 = d_in[14];
  const void* uW2 = d_in[15];
  const void* ub2 = d_in[16];
  const void* oW1 = d_in[17];
  const void* ob1 = d_in[18];
  const void* oW2 = d_in[19];
  const void* ob2 = d_in[20];

  char* ws = (char*)d_ws;
  const size_t OFF_E = 0;
  const size_t OFF_MSUM = OFF_E + (size_t)NE * HD * 2;
  const size_t OFF_FEAT = OFF_MSUM + (size_t)NN * HD * 4;
  const size_t OFF_SACC = OFF_FEAT + (size_t)NN * HD * 2;
  const size_t OFF_MX = OFF_SACC + (size_t)NB * HD * 4;
  const size_t OFF_CNT = OFF_MX + (size_t)NB * HD * 4;
  const size_t OFF_DEG = OFF_CNT + 1024;
  const size_t OFF_ROWPTR = OFF_DEG + (size_t)NN * 4;
  const size_t OFF_CURSOR = OFF_ROWPTR + (size_t)(NN + 2) * 4;
  const size_t OFF_EIDS = OFF_CURSOR + (size_t)NN * 4;
  const size_t OFF_SRCS = OFF_EIDS + (size_t)NE * 4;
  const size_t OFF_DSTS = OFF_SRCS + (size_t)NE * 4;
  const size_t OFF_WT1 = OFF_DSTS + (size_t)NE * 4;
  const size_t OFF_WT2P = OFF_WT1 + (size_t)NL * 3 * PANEL * 2;
  const size_t OFF_WTU1 = OFF_WT2P + (size_t)NL * PANEL * 2;
  const size_t OFF_WTU2P = OFF_WTU1 + (size_t)NL * PANEL * 2;
  const size_t OFF_WTO1 = OFF_WTU2P + (size_t)NL * PANEL * 2;
  const size_t OFF_WTO2P = OFF_WTO1 + (size_t)PANEL * 2;
  const size_t OFF_FLAG = OFF_WTO2P + (size_t)PANEL * 2;
  const size_t OFF_V0 = OFF_FLAG + 64;

  u16* e = (u16*)(ws + OFF_E);
  float* msum = (float*)(ws + OFF_MSUM);
  u16* feat = (u16*)(ws + OFF_FEAT);
  float* sacc = (float*)(ws + OFF_SACC);
  u32* mx = (u32*)(ws + OFF_MX);
  float* cnt = (float*)(ws + OFF_CNT);
  u32* deg = (u32*)(ws + OFF_DEG);
  int* rowptr = (int*)(ws + OFF_ROWPTR);
  int* cursor = (int*)(ws + OFF_CURSOR);
  int* eids = (int*)(ws + OFF_EIDS);
  int* src_s = (int*)(ws + OFF_SRCS);
  int* dst_s = (int*)(ws + OFF_DSTS);
  u16* Wt1 = (u16*)(ws + OFF_WT1);
  u16* Wt2p = (u16*)(ws + OFF_WT2P);
  u16* Wtu1 = (u16*)(ws + OFF_WTU1);
  u16* Wtu2p = (u16*)(ws + OFF_WTU2P);
  u16* Wto1 = (u16*)(ws + OFF_WTO1);
  u16* Wto2p = (u16*)(ws + OFF_WTO2P);
  int* flag = (int*)(ws + OFF_FLAG);
  float* v0f = (float*)(ws + OFF_V0);

  // zero sacc + mx + cnt + deg
  hipMemsetAsync(ws + OFF_SACC, 0,
                 (size_t)NB * HD * 4 * 2 + 1024 + (size_t)NN * 4, stream);
  // zero msum once (layer 0); k_node re-zeroes it for subsequent layers
  hipMemsetAsync(msum, 0, (size_t)NN * HD * 4, stream);

  k_detect<<<1, 64, 0, stream>>>((const u16*)We, flag);
  k_v0<<<1, 128, 0, stream>>>(nemb, mW1, flag, v0f);
  k_prep<<<256, 256, 0, stream>>>(mW1, mW2, uW1, uW2, oW1, oW2, flag,
                                  Wt1, Wt2p, Wtu1, Wtu2p, Wto1, Wto2p);
  k_featinit<<<(NN * HD / 8) / 256, 256, 0, stream>>>(nemb, flag, feat);

  // CSR by dst (sorted edge order used everywhere)
  k_csr_deg<<<NE / 256, 256, 0, stream>>>(dst, deg);
  k_csr_scan<<<1, 1024, 0, stream>>>(deg, rowptr, cursor);
  k_csr_scatter<<<NE / 256, 256, 0, stream>>>(dst, src, cursor, eids, src_s, dst_s);

  k_encode<<<NE / 256, 256, 0, stream>>>(d_d, eids, We, be, flag, e);

  for (int l = 0; l < NL; l++) {
    if (l == 0)
      k_edge<true><<<NE / 128, 256, 0, stream>>>(feat, e, src_s, dst_s, Wt1, Wt2p,
                                                 mb1, mb2, sW, sb, flag, v0f, msum, l);
    else
      k_edge<false><<<NE / 128, 256, 0, stream>>>(feat, e, src_s, dst_s, Wt1, Wt2p,
                                                  mb1, mb2, sW, sb, flag, v0f, msum, l);
    if (l < NL - 1)
      k_node<false><<<NN / 32, 64, 0, stream>>>(feat, msum, Wtu1, Wtu2p, ub1, ub2,
                                                flag, l, seg, Wto1, Wto2p, ob1, ob2,
                                                sacc, mx, cnt);
    else
      k_node<true><<<NN / 32, 64, 0, stream>>>(feat, msum, Wtu1, Wtu2p, ub1, ub2,
                                               flag, l, seg, Wto1, Wto2p, ob1, ob2,
                                               sacc, mx, cnt);
  }
  k_final<<<(NB * 384) / 256, 256, 0, stream>>>(sacc, mx, cnt, flag, d_out);
}

// Round 16
// 680.286 us; speedup vs baseline: 1.1906x; 1.0553x over previous
//
#include <hip/hip_runtime.h>
#include <hip/hip_bf16.h>

#define NN 32768   // nodes
#define NB 256     // graphs
#define HD 128     // hidden
#define NL 4       // layers
#define NE 262144  // edges

typedef short bf16x8 __attribute__((ext_vector_type(8)));
typedef float f32x4 __attribute__((ext_vector_type(4)));
typedef unsigned short u16;
typedef unsigned int u32;

__device__ __forceinline__ float bf2f(u16 u) {
  return __uint_as_float(((u32)u) << 16);
}
__device__ __forceinline__ u16 f2bf(float f) {
  u32 x = __float_as_uint(f);
  u32 r = x + 0x7FFFu + ((x >> 16) & 1u);
  return (u16)(r >> 16);
}
__device__ __forceinline__ u32 pk2(float a, float b) {
  __hip_bfloat162 h = __float22bfloat162_rn(make_float2(a, b));
  return *reinterpret_cast<u32*>(&h);
}
__device__ __forceinline__ float siluf(float x) {
  return x * __builtin_amdgcn_rcpf(1.0f + __expf(-x));
}
__device__ __forceinline__ float sigf(float x) {
  return __builtin_amdgcn_rcpf(1.0f + __expf(-x));
}
__device__ __forceinline__ u32 ordu(float f) {
  u32 b = __float_as_uint(f);
  return (b & 0x80000000u) ? ~b : (b | 0x80000000u);
}

// ---- adaptive input loads: mode 1 = f32 inputs, mode 0 = bf16 inputs ----
__device__ __forceinline__ float ldinf(const void* p, size_t i, int mode) {
  return mode ? ((const float*)p)[i] : bf2f(((const u16*)p)[i]);
}
__device__ __forceinline__ u16 ldinb(const void* p, size_t i, int mode) {
  return mode ? f2bf(((const float*)p)[i]) : ((const u16*)p)[i];
}

// ---- dtype detect + layer-0 bias fold (merged, single block) ----
// v0[n] = nemb @ (W1[0:128,n] + W1[128:256,n])
__global__ void k_detect_v0(const u16* __restrict__ Weraw,
                            const void* __restrict__ nemb,
                            const void* __restrict__ mW1,
                            int* __restrict__ flag, float* __restrict__ v0f) {
  __shared__ int smode;
  if (threadIdx.x == 0) {
    int cnt = 0;
    for (int i = 0; i < 256; i++) {
      u16 u = Weraw[2 * i];
      u32 e = (u >> 7) & 0xFFu;
      if (e >= 112u && e <= 126u) cnt++;
    }
    const int m = (cnt >= 128) ? 0 : 1;
    *flag = m;
    smode = m;
  }
  __syncthreads();
  const int mode = smode;
  const int n = threadIdx.x;  // 128
  float s = 0.f;
  for (int k = 0; k < 256; k++)
    s += ldinf(nemb, k & 127, mode) * ldinf(mW1, (size_t)k * HD + n, mode);
  v0f[n] = s;
}

// ================= SLOT ORDER / SORTED EDGES / XCD CHUNKING =================
// slot s <-> h=(s&7)*16+(s>>3); weight panels fold perm (klog);
// edge arrays dst-sorted; block ids chunk-swizzled per XCD.
#define PANEL 16384  // shorts per packed 128x128 weight panel

// ---------------- CSR build (by dst) ----------------
__global__ __launch_bounds__(256) void k_csr_deg(const int* __restrict__ dstp,
                                                 u32* __restrict__ deg) {
  const int i = blockIdx.x * 256 + threadIdx.x;
  atomicAdd(&deg[dstp[i]], 1u);
}

__global__ __launch_bounds__(1024) void k_csr_scan(const u32* __restrict__ deg,
                                                   int* __restrict__ rowptr,
                                                   int* __restrict__ cursor) {
  __shared__ int part[1024];
  const int t = threadIdx.x;
  int loc[32];
  int s = 0;
#pragma unroll
  for (int j = 0; j < 32; j++) { loc[j] = s; s += (int)deg[t * 32 + j]; }
  part[t] = s;
  __syncthreads();
  int inc = s;
  for (int off = 1; off < 1024; off <<= 1) {
    int tmp = (t >= off) ? part[t - off] : 0;
    __syncthreads();
    part[t] += tmp;
    __syncthreads();
  }
  const int base = part[t] - inc;
#pragma unroll
  for (int j = 0; j < 32; j++) {
    rowptr[t * 32 + j] = base + loc[j];
    cursor[t * 32 + j] = base + loc[j];
  }
  if (t == 1023) rowptr[NN] = part[1023];
}

// ---- fused CSR scatter + edge-feature encode (writes e[pos] directly) -------
__global__ __launch_bounds__(256) void k_scatter_encode(
    const int* __restrict__ dstp, const int* __restrict__ srcp,
    int* __restrict__ cursor, int* __restrict__ src_s, int* __restrict__ dst_s,
    const void* __restrict__ d, const void* __restrict__ We,
    const void* __restrict__ be, const int* __restrict__ flagp,
    u16* __restrict__ e) {
  const int mode = *flagp;
  __shared__ float sW[9 * HD];
  __shared__ float sb[HD];
  for (int i = threadIdx.x; i < 9 * HD; i += 256) sW[i] = ldinf(We, i, mode);
  for (int i = threadIdx.x; i < HD; i += 256) sb[i] = ldinf(be, i, mode);
  __syncthreads();
  const int i = blockIdx.x * 256 + threadIdx.x;  // original edge id
  const int dn = dstp[i];
  const int pos = atomicAdd(&cursor[dn], 1);     // sorted position
  src_s[pos] = srcp[i];
  dst_s[pos] = dn;
  const float dv = ldinf(d, i, mode);
  float de[9];
#pragma unroll
  for (int k = 0; k < 4; k++) {
    float x = dv * (1.0f / (float)(1 << k));
    de[k] = __sinf(x);
    de[4 + k] = __cosf(x);
  }
  de[8] = dv;
  u16* erow = e + (size_t)pos * HD;
#pragma unroll
  for (int g = 0; g < 16; g++) {   // granule g: slots 8g+j hold h=j*16+g
    u32 ou[4];
#pragma unroll
    for (int p = 0; p < 4; p++) {
      float vv[2];
#pragma unroll
      for (int t = 0; t < 2; t++) {
        const int h = (2 * p + t) * 16 + g;
        float a = sb[h];
#pragma unroll
        for (int k = 0; k < 9; k++) a += de[k] * sW[k * HD + h];
        vv[t] = siluf(siluf(a));
      }
      ou[p] = pk2(vv[0], vv[1]);
    }
    ((int4*)erow)[g] = make_int4((int)ou[0], (int)ou[1], (int)ou[2], (int)ou[3]);
  }
}

// ---------------- per-wave GEMM pieces ----------------
template <int MT>
__device__ __forceinline__ void acc_zero(f32x4 (&acc)[MT][8]) {
#pragma unroll
  for (int mt = 0; mt < MT; mt++)
#pragma unroll
    for (int nt = 0; nt < 8; nt++) acc[mt][nt] = f32x4{0.f, 0.f, 0.f, 0.f};
}

__device__ __forceinline__ void load_a2(const u16* __restrict__ A0,
                                        const size_t* rowoff, int kg,
                                        bf16x8 (&a)[2][4]) {
#pragma unroll
  for (int ks = 0; ks < 4; ks++)
#pragma unroll
    for (int mt = 0; mt < 2; mt++)
      a[mt][ks] = *(const bf16x8*)&A0[rowoff[mt] + ks * 32 + kg * 8];
}

__device__ __forceinline__ void gemm_lds2(const bf16x8 (&a)[2][4],
                                          const short* sB, int l,
                                          f32x4 (&acc)[2][8]) {
#pragma unroll
  for (int ks = 0; ks < 4; ks++)
#pragma unroll
    for (int nt = 0; nt < 8; nt++) {
      bf16x8 b = *(const bf16x8*)&sB[((nt * 4 + ks) * 64 + l) * 8];
#pragma unroll
      for (int mt = 0; mt < 2; mt++)
        acc[mt][nt] = __builtin_amdgcn_mfma_f32_16x16x32_bf16(a[mt][ks], b, acc[mt][nt], 0, 0, 0);
    }
}

template <int MT>
__device__ __forceinline__ void wave_gemm_p(const short* lAw, const u16* __restrict__ Bp,
                                            int l, int c, int kg, f32x4 (&acc)[MT][8]) {
#pragma unroll
  for (int ks = 0; ks < 4; ks++) {
    bf16x8 a[MT];
#pragma unroll
    for (int mt = 0; mt < MT; mt++) {
      const int r = mt * 16 + c;
      const int k = ks * 32 + kg * 8;
      a[mt] = *(const bf16x8*)&lAw[r * HD + (k ^ ((r & 7) << 3))];
    }
#pragma unroll
    for (int nt = 0; nt < 8; nt++) {
      bf16x8 b = *(const bf16x8*)&Bp[(size_t)((nt * 4 + ks) * 64 + l) * 8];
#pragma unroll
      for (int mt = 0; mt < MT; mt++)
        acc[mt][nt] = __builtin_amdgcn_mfma_f32_16x16x32_bf16(a[mt], b, acc[mt][nt], 0, 0, 0);
    }
  }
}

template <int MT, bool SILU>
__device__ __forceinline__ void wave_pack(short* lAw, int c, int kg,
                                          f32x4 (&acc)[MT][8], const float* bias) {
#pragma unroll
  for (int mt = 0; mt < MT; mt++) {
#pragma unroll
    for (int rr = 0; rr < 4; rr++) {
      const int row = mt * 16 + kg * 4 + rr;
      u32 ou[4];
#pragma unroll
      for (int p = 0; p < 4; p++) {
        float x0 = acc[mt][2 * p][rr] + bias[2 * p];
        float x1 = acc[mt][2 * p + 1][rr] + bias[2 * p + 1];
        if (SILU) { x0 = siluf(x0); x1 = siluf(x1); }
        ou[p] = pk2(x0, x1);
      }
      ((int4*)(lAw + row * HD))[c ^ (row & 7)] =
          make_int4((int)ou[0], (int)ou[1], (int)ou[2], (int)ou[3]);
    }
  }
}

__device__ __forceinline__ void stage_panel(const u16* __restrict__ P,
                                            short* sB, int tid) {
#pragma unroll
  for (int it = 0; it < 8; it++) {
    const int idx = (it * 256 + tid) * 8;
    *(int4*)&sB[idx] = *(const int4*)&P[idx];
  }
}

// ---------------- weight prep: pack panels, fold slot permutation -------------
__global__ __launch_bounds__(256) void k_prep(
    const void* __restrict__ mW1, const void* __restrict__ mW2,
    const void* __restrict__ uW1, const void* __restrict__ uW2,
    const void* __restrict__ oW1, const void* __restrict__ oW2,
    const int* __restrict__ flagp,
    u16* __restrict__ Wt1, u16* __restrict__ Wt2p,
    u16* __restrict__ Wtu1, u16* __restrict__ Wtu2p,
    u16* __restrict__ Wto1, u16* __restrict__ Wto2p) {
  const int mode = *flagp;
  const int tid = blockIdx.x * blockDim.x + threadIdx.x;
  const int stride = gridDim.x * blockDim.x;
  for (int i = tid; i < NL * 3 * PANEL; i += stride) {
    const int l = i / (3 * PANEL), r = i % (3 * PANEL);
    const int chunk = r / PANEL, r2 = r % PANEL;
    const int nt = r2 / 2048, ks = (r2 % 2048) / 512;
    const int lane = (r2 % 512) / 8, j = r2 % 8;
    const int s = ks * 32 + (lane >> 4) * 8 + j;
    const int klog = ((s & 7) << 4) | (s >> 3);
    const int n = nt * 16 + (lane & 15);
    Wt1[i] = ldinb(mW1, ((size_t)l * 384 + chunk * 128 + klog) * HD + n, mode);
  }
  for (int i = tid; i < NL * PANEL; i += stride) {
    const int l = i / PANEL, r = i % PANEL;
    const int nt = r / 2048, ks = (r % 2048) / 512;
    const int lane = (r % 512) / 8, j = r % 8;
    const int s = ks * 32 + (lane >> 4) * 8 + j;
    const int klog = ((s & 7) << 4) | (s >> 3);
    const int n = nt * 16 + (lane & 15);
    Wt2p[i] = ldinb(mW2, ((size_t)l * HD + klog) * HD + n, mode);
    Wtu1[i] = ldinb(uW1, ((size_t)l * HD + klog) * HD + n, mode);
    Wtu2p[i] = ldinb(uW2, ((size_t)l * HD + klog) * HD + n, mode);
  }
  for (int i = tid; i < PANEL; i += stride) {
    const int nt = i / 2048, ks = (i % 2048) / 512;
    const int lane = (i % 512) / 8, j = i % 8;
    const int s = ks * 32 + (lane >> 4) * 8 + j;
    const int klog = ((s & 7) << 4) | (s >> 3);
    const int n = nt * 16 + (lane & 15);
    Wto1[i] = ldinb(oW1, (size_t)klog * HD + n, mode);
    Wto2p[i] = ldinb(oW2, (size_t)klog * HD + n, mode);
  }
}

// ---------------- feat init (slot order) ----------------
__global__ __launch_bounds__(256) void k_featinit(const void* __restrict__ nemb,
                                                  const int* __restrict__ flagp,
                                                  u16* __restrict__ feat) {
  const int mode = *flagp;
  const int i = blockIdx.x * 256 + threadIdx.x;
  const int g = i & 15;
  u32 ou[4];
#pragma unroll
  for (int p = 0; p < 4; p++) {
    u16 a = ldinb(nemb, (2 * p) * 16 + g, mode);
    u16 b = ldinb(nemb, (2 * p + 1) * 16 + g, mode);
    ou[p] = (u32)a | ((u32)b << 16);
  }
  ((int4*)feat)[i] = make_int4((int)ou[0], (int)ou[1], (int)ou[2], (int)ou[3]);
}

// ---------------- edge message layer: 4-wave, LDS-B GEMM1, sB reused for h1/m -
// FIRST (layer 0): feat[src]=feat[dst]=nemb -> folded into bias via v0f.
// LDS = 32KB sB + ~1KB -> 4 blocks/CU (16 waves/CU), barriers 7 -> 4.
template <bool FIRST>
__global__ __launch_bounds__(256, 4) void k_edge(
    const u16* __restrict__ feat, u16* __restrict__ e,
    const int* __restrict__ src_s, const int* __restrict__ dst_s,
    const u16* __restrict__ Wt1, const u16* __restrict__ Wt2p,
    const void* __restrict__ b1g, const void* __restrict__ b2g,
    const void* __restrict__ softW, const void* __restrict__ softb,
    const int* __restrict__ flagp, const float* __restrict__ v0f,
    float* __restrict__ msum, int layer) {
  __shared__ __align__(16) short sB[PANEL];   // W1 panels; then 4x32-row h1/m
  __shared__ float swg[128];
  __shared__ int sdst[128];
  const int mode = *flagp;
  const int tid = threadIdx.x;
  const int l = tid & 63, wid = tid >> 6;
  const int c = l & 15, kg = l >> 4;
  const int bid = (int)blockIdx.x;
  const int blkB = (((bid & 7) << 8) | (bid >> 3)) * 128;
  const int blk = blkB + wid * 32;
  short* lMw = sB + wid * 32 * HD;   // wave-private slice AFTER GEMM1 done
  float* swgw = swg + wid * 32;
  int* sdstw = sdst + wid * 32;

  if (l < 32) sdstw[l] = dst_s[blk + l];

  size_t offS[2], offD[2], offE[2];
#pragma unroll
  for (int mt = 0; mt < 2; mt++) {
    const int eidx = blk + mt * 16 + c;
    if (!FIRST) {
      offS[mt] = (size_t)src_s[eidx] * HD;
      offD[mt] = (size_t)dst_s[eidx] * HD;
    }
    offE[mt] = (size_t)eidx * HD;
  }

  const u16* W1l = Wt1 + (size_t)layer * 3 * PANEL;
  const u16* W2l = Wt2p + (size_t)layer * PANEL;
  float bias1[8], bias2[8], swf[8];
#pragma unroll
  for (int nt = 0; nt < 8; nt++) {
    bias1[nt] = ldinf(b1g, layer * HD + nt * 16 + c, mode);
    if (FIRST) bias1[nt] += v0f[nt * 16 + c];
    bias2[nt] = ldinf(b2g, layer * HD + nt * 16 + c, mode);
    swf[nt] = ldinf(softW, (size_t)layer * HD + nt * 16 + c, mode);
  }
  const float sbv = ldinf(softb, layer, mode);

  f32x4 acc[2][8];
  acc_zero<2>(acc);
  bf16x8 a[2][4];

  if (!FIRST) {
    load_a2(feat, offS, kg, a);
    stage_panel(W1l, sB, tid);
    __syncthreads();
    gemm_lds2(a, sB, l, acc);
    __syncthreads();
    load_a2(feat, offD, kg, a);
    stage_panel(W1l + PANEL, sB, tid);
    __syncthreads();
    gemm_lds2(a, sB, l, acc);
    __syncthreads();
  }
  load_a2(e, offE, kg, a);
  stage_panel(W1l + 2 * PANEL, sB, tid);
  __syncthreads();
  gemm_lds2(a, sB, l, acc);
  __syncthreads();   // all waves done reading W1c2 -> sB reusable per-wave

  // h1 into own sB slice (wave-private; in-order DS pipe, no extra syncs)
  wave_pack<2, true>(lMw, c, kg, acc, bias1);

  // GEMM2: A from own slice, B from global packed W2 (L2-hot)
  acc_zero<2>(acc);
  wave_gemm_p<2>(lMw, W2l, l, c, kg, acc);

  // ---- fused: pack m -> lMw (over h1), gate, e += m ----
  float wred[2][4];
#pragma unroll
  for (int mt = 0; mt < 2; mt++) {
#pragma unroll
    for (int rr = 0; rr < 4; rr++) {
      const int row = mt * 16 + kg * 4 + rr;
      int4* erow4 = (int4*)(e + (size_t)(blk + row) * HD);
      const int4 eo = erow4[c];
      const u32 eu[4] = {(u32)eo.x, (u32)eo.y, (u32)eo.z, (u32)eo.w};
      float mv[8];
      float wp = 0.f;
#pragma unroll
      for (int nt = 0; nt < 8; nt++) {
        mv[nt] = siluf(acc[mt][nt][rr] + bias2[nt]);
        wp += mv[nt] * swf[nt];
      }
      u32 mo[4], ou[4];
#pragma unroll
      for (int p = 0; p < 4; p++) {
        mo[p] = pk2(mv[2 * p], mv[2 * p + 1]);
        ou[p] = pk2(bf2f((u16)(eu[p] & 0xffffu)) + mv[2 * p],
                    bf2f((u16)(eu[p] >> 16)) + mv[2 * p + 1]);
      }
      ((int4*)(lMw + row * HD))[c ^ (row & 7)] =
          make_int4((int)mo[0], (int)mo[1], (int)mo[2], (int)mo[3]);
      erow4[c] = make_int4((int)ou[0], (int)ou[1], (int)ou[2], (int)ou[3]);
      wp += __shfl_xor(wp, 1);
      wp += __shfl_xor(wp, 2);
      wp += __shfl_xor(wp, 4);
      wp += __shfl_xor(wp, 8);
      wred[mt][rr] = wp;
    }
  }
#pragma unroll
  for (int mt = 0; mt < 2; mt++)
#pragma unroll
    for (int rr = 0; rr < 4; rr++)
      if (c == mt * 4 + rr) swgw[mt * 16 + kg * 4 + rr] = sigf(wred[mt][rr] + sbv);

  // ---- msum run-aggregation (lane l owns slots l and l+64) ----
  const int gM = ((l >> 3) << 3);
  const int em = l & 7;
  float a0 = 0.f, a1 = 0.f;
  int cur = sdstw[0];
  for (int r = 0; r < 32; r++) {
    const int dn = sdstw[r];
    if (dn != cur) {
      atomicAdd(&msum[(size_t)cur * HD + l], a0);
      atomicAdd(&msum[(size_t)cur * HD + l + 64], a1);
      a0 = 0.f; a1 = 0.f; cur = dn;
    }
    const int rx = (r & 7) << 3;
    const float wgr = swgw[r];
    a0 += wgr * bf2f((u16)lMw[r * HD + (gM ^ rx) + em]);
    a1 += wgr * bf2f((u16)lMw[r * HD + (gM ^ rx) + 64 + em]);
  }
  atomicAdd(&msum[(size_t)cur * HD + l], a0);
  atomicAdd(&msum[(size_t)cur * HD + l + 64], a1);
}

// ---------------- node update; LAST also runs the out-MLP + readout -----------
template <bool LAST>
__global__ __launch_bounds__(64, 4) void k_node(
    u16* __restrict__ feat, float* __restrict__ msum,
    const u16* __restrict__ Wtu1, const u16* __restrict__ Wtu2p,
    const void* __restrict__ b1g, const void* __restrict__ b2g,
    const int* __restrict__ flagp, int layer,
    const int* __restrict__ seg,
    const u16* __restrict__ Wto1, const u16* __restrict__ Wto2p,
    const void* __restrict__ ob1, const void* __restrict__ ob2,
    float* __restrict__ sacc, u32* __restrict__ mxacc, float* __restrict__ cnt) {
  __shared__ __align__(16) short lA[32 * HD];
  __shared__ int sseg[32];
  const int mode = *flagp;
  const int l = threadIdx.x;
  const int c = l & 15, kg = l >> 4;
  short* lAw = lA;
  const int bid = (int)blockIdx.x;
  const int blkn = (((bid & 7) << 7) | (bid >> 3)) * 32;
  const u16* W1l = Wtu1 + (size_t)layer * PANEL;
  const u16* W2l = Wtu2p + (size_t)layer * PANEL;
  float bias1[8], bias2[8];
#pragma unroll
  for (int nt = 0; nt < 8; nt++) {
    bias1[nt] = ldinf(b1g, layer * HD + nt * 16 + c, mode);
    bias2[nt] = ldinf(b2g, layer * HD + nt * 16 + c, mode);
  }
  if (LAST && l < 32) sseg[l] = seg[blkn + l];

  // stage upd_in = feat + msum, then zero msum
  const float4 z4 = make_float4(0.f, 0.f, 0.f, 0.f);
#pragma unroll
  for (int rp = 0; rp < 8; rp++) {
    const int r = rp * 4 + (l >> 4);
    const int g = l & 15;
    const int4 fv = ((const int4*)(feat + (size_t)(blkn + r) * HD))[g];
    const u32 uu[4] = {(u32)fv.x, (u32)fv.y, (u32)fv.z, (u32)fv.w};
    float4* mrow4 = (float4*)(msum + (size_t)(blkn + r) * HD);
    const float4 ma = mrow4[2 * g];
    const float4 mb = mrow4[2 * g + 1];
    mrow4[2 * g] = z4;
    mrow4[2 * g + 1] = z4;
    const float mm[8] = {ma.x, ma.y, ma.z, ma.w, mb.x, mb.y, mb.z, mb.w};
    u32 ou[4];
#pragma unroll
    for (int p = 0; p < 4; p++) {
      ou[p] = pk2(bf2f((u16)(uu[p] & 0xffffu)) + mm[2 * p],
                  bf2f((u16)(uu[p] >> 16)) + mm[2 * p + 1]);
    }
    ((int4*)(lAw + r * HD))[g ^ (r & 7)] =
        make_int4((int)ou[0], (int)ou[1], (int)ou[2], (int)ou[3]);
  }
  __syncthreads();
  f32x4 acc[2][8];
  acc_zero<2>(acc);
  wave_gemm_p<2>(lAw, W1l, l, c, kg, acc);
  __syncthreads();
  wave_pack<2, true>(lAw, c, kg, acc, bias1);
  __syncthreads();
  acc_zero<2>(acc);
  wave_gemm_p<2>(lAw, W2l, l, c, kg, acc);
  __syncthreads();

  // residual: newfeat = feat + (acc + bias2)
#pragma unroll
  for (int mt = 0; mt < 2; mt++) {
#pragma unroll
    for (int rr = 0; rr < 4; rr++) {
      const int row = mt * 16 + kg * 4 + rr;
      int4* frow4 = (int4*)(feat + (size_t)(blkn + row) * HD);
      const int4 fo = frow4[c];
      const u32 fu[4] = {(u32)fo.x, (u32)fo.y, (u32)fo.z, (u32)fo.w};
      u32 ou[4];
#pragma unroll
      for (int p = 0; p < 4; p++) {
        const float x0 = acc[mt][2 * p][rr] + bias2[2 * p];
        const float x1 = acc[mt][2 * p + 1][rr] + bias2[2 * p + 1];
        ou[p] = pk2(bf2f((u16)(fu[p] & 0xffffu)) + x0,
                    bf2f((u16)(fu[p] >> 16)) + x1);
      }
      const int4 nv = make_int4((int)ou[0], (int)ou[1], (int)ou[2], (int)ou[3]);
      if (LAST) {
        ((int4*)(lAw + row * HD))[c ^ (row & 7)] = nv;
      } else {
        frow4[c] = nv;
      }
    }
  }

  if (LAST) {
    __syncthreads();
    float ob1r[8], ob2r[8];
#pragma unroll
    for (int nt = 0; nt < 8; nt++) {
      ob1r[nt] = ldinf(ob1, nt * 16 + c, mode);
      ob2r[nt] = ldinf(ob2, nt * 16 + c, mode);
    }
    acc_zero<2>(acc);
    wave_gemm_p<2>(lAw, Wto1, l, c, kg, acc);
    __syncthreads();
    wave_pack<2, true>(lAw, c, kg, acc, ob1r);
    __syncthreads();
    acc_zero<2>(acc);
    wave_gemm_p<2>(lAw, Wto2p, l, c, kg, acc);
    __syncthreads();
    wave_pack<2, false>(lAw, c, kg, acc, ob2r);
    __syncthreads();

    const int gL = l >> 2;
    const int eoff = (l & 3) * 2;
    const bool uniform = (sseg[0] == sseg[31]);
    if (uniform) {
      const int g = sseg[0];
      float s1 = 0.f, s2 = 0.f, x1 = -3.402823e38f, x2 = -3.402823e38f;
#pragma unroll 4
      for (int r = 0; r < 32; r++) {
        const u32 mv = *(const u32*)&lAw[r * HD + ((gL ^ (r & 7)) << 3) + eoff];
        const float v1 = bf2f((u16)(mv & 0xffffu));
        const float v2 = bf2f((u16)(mv >> 16));
        s1 += v1; s2 += v2;
        x1 = fmaxf(x1, v1); x2 = fmaxf(x2, v2);
      }
      atomicAdd(&sacc[(size_t)g * HD + 2 * l], s1);
      atomicAdd(&sacc[(size_t)g * HD + 2 * l + 1], s2);
      atomicMax(&mxacc[(size_t)g * HD + 2 * l], ordu(x1));
      atomicMax(&mxacc[(size_t)g * HD + 2 * l + 1], ordu(x2));
      if (l == 0) atomicAdd(&cnt[g], 32.0f);
    } else {
      if (l < 32) atomicAdd(&cnt[sseg[l]], 1.0f);
#pragma unroll 4
      for (int r = 0; r < 32; r++) {
        const u32 mv = *(const u32*)&lAw[r * HD + ((gL ^ (r & 7)) << 3) + eoff];
        const float v1 = bf2f((u16)(mv & 0xffffu));
        const float v2 = bf2f((u16)(mv >> 16));
        const int g = sseg[r];
        atomicAdd(&sacc[(size_t)g * HD + 2 * l], v1);
        atomicAdd(&sacc[(size_t)g * HD + 2 * l + 1], v2);
        atomicMax(&mxacc[(size_t)g * HD + 2 * l], ordu(v1));
        atomicMax(&mxacc[(size_t)g * HD + 2 * l + 1], ordu(v2));
      }
    }
  }
}

// ---------------- finalize: un-permute slot order -> h order ------------------
__global__ __launch_bounds__(256) void k_final(const float* __restrict__ sacc,
                                               const u32* __restrict__ mxacc,
                                               const float* __restrict__ cnt,
                                               const int* __restrict__ flagp,
                                               void* __restrict__ out) {
  const int mode = *flagp;
  const int i = blockIdx.x * 256 + threadIdx.x;
  const int b = i / 384, j = i % 384;
  float v;
  if (j < HD) {
    const int p = ((j & 15) << 3) | (j >> 4);
    v = sacc[b * HD + p];
  } else if (j < 2 * HD) {
    const int t = j - HD;
    const int p = ((t & 15) << 3) | (t >> 4);
    v = sacc[b * HD + p] / fmaxf(cnt[b], 1.0f);
  } else {
    const int t = j - 2 * HD;
    const int p = ((t & 15) << 3) | (t >> 4);
    u32 u = mxacc[b * HD + p];
    u32 bits = (u >> 31) ? (u ^ 0x80000000u) : ~u;
    v = __uint_as_float(bits);
  }
  if (mode) ((float*)out)[i] = v;
  else ((u16*)out)[i] = f2bf(v);
}

extern "C" void kernel_launch(void* const* d_in, const int* in_sizes, int n_in,
                              void* d_out, int out_size, void* d_ws, size_t ws_size,
                              hipStream_t stream) {
  const void* d_d = d_in[0];
  const int* src = (const int*)d_in[1];
  const int* dst = (const int*)d_in[2];
  const int* seg = (const int*)d_in[3];
  const void* nemb = d_in[4];
  const void* We = d_in[5];
  const void* be = d_in[6];
  const void* mW1 = d_in[7];
  const void* mb1 = d_in[8];
  const void* mW2 = d_in[9];
  const void* mb2 = d_in[10];
  const void* sW = d_in[11];
  const void* sb = d_in[12];
  const void* uW1 = d_in[13];
  const void* ub1 = d_in[14];
  const void* uW2 = d_in[15];
  const void* ub2 = d_in[16];
  const void* oW1 = d_in[17];
  const void* ob1 = d_in[18];
  const void* oW2 = d_in[19];
  const void* ob2 = d_in[20];

  char* ws = (char*)d_ws;
  const size_t OFF_E = 0;
  const size_t OFF_MSUM = OFF_E + (size_t)NE * HD * 2;
  const size_t OFF_FEAT = OFF_MSUM + (size_t)NN * HD * 4;
  const size_t OFF_SACC = OFF_FEAT + (size_t)NN * HD * 2;
  const size_t OFF_MX = OFF_SACC + (size_t)NB * HD * 4;
  const size_t OFF_CNT = OFF_MX + (size_t)NB * HD * 4;
  const size_t OFF_DEG = OFF_CNT + 1024;
  const size_t OFF_ROWPTR = OFF_DEG + (size_t)NN * 4;
  const size_t OFF_CURSOR = OFF_ROWPTR + (size_t)(NN + 2) * 4;
  const size_t OFF_SRCS = OFF_CURSOR + (size_t)NN * 4;
  const size_t OFF_DSTS = OFF_SRCS + (size_t)NE * 4;
  const size_t OFF_WT1 = OFF_DSTS + (size_t)NE * 4;
  const size_t OFF_WT2P = OFF_WT1 + (size_t)NL * 3 * PANEL * 2;
  const size_t OFF_WTU1 = OFF_WT2P + (size_t)NL * PANEL * 2;
  const size_t OFF_WTU2P = OFF_WTU1 + (size_t)NL * PANEL * 2;
  const size_t OFF_WTO1 = OFF_WTU2P + (size_t)NL * PANEL * 2;
  const size_t OFF_WTO2P = OFF_WTO1 + (size_t)PANEL * 2;
  const size_t OFF_FLAG = OFF_WTO2P + (size_t)PANEL * 2;
  const size_t OFF_V0 = OFF_FLAG + 64;

  u16* e = (u16*)(ws + OFF_E);
  float* msum = (float*)(ws + OFF_MSUM);
  u16* feat = (u16*)(ws + OFF_FEAT);
  float* sacc = (float*)(ws + OFF_SACC);
  u32* mx = (u32*)(ws + OFF_MX);
  float* cnt = (float*)(ws + OFF_CNT);
  u32* deg = (u32*)(ws + OFF_DEG);
  int* rowptr = (int*)(ws + OFF_ROWPTR);
  int* cursor = (int*)(ws + OFF_CURSOR);
  int* src_s = (int*)(ws + OFF_SRCS);
  int* dst_s = (int*)(ws + OFF_DSTS);
  u16* Wt1 = (u16*)(ws + OFF_WT1);
  u16* Wt2p = (u16*)(ws + OFF_WT2P);
  u16* Wtu1 = (u16*)(ws + OFF_WTU1);
  u16* Wtu2p = (u16*)(ws + OFF_WTU2P);
  u16* Wto1 = (u16*)(ws + OFF_WTO1);
  u16* Wto2p = (u16*)(ws + OFF_WTO2P);
  int* flag = (int*)(ws + OFF_FLAG);
  float* v0f = (float*)(ws + OFF_V0);

  // zero sacc + mx + cnt + deg
  hipMemsetAsync(ws + OFF_SACC, 0,
                 (size_t)NB * HD * 4 * 2 + 1024 + (size_t)NN * 4, stream);
  // zero msum once (layer 0); k_node re-zeroes it for subsequent layers
  hipMemsetAsync(msum, 0, (size_t)NN * HD * 4, stream);

  k_detect_v0<<<1, 128, 0, stream>>>((const u16*)We, nemb, mW1, flag, v0f);
  k_prep<<<256, 256, 0, stream>>>(mW1, mW2, uW1, uW2, oW1, oW2, flag,
                                  Wt1, Wt2p, Wtu1, Wtu2p, Wto1, Wto2p);
  k_featinit<<<(NN * HD / 8) / 256, 256, 0, stream>>>(nemb, flag, feat);

  // CSR by dst + fused encode into sorted e
  k_csr_deg<<<NE / 256, 256, 0, stream>>>(dst, deg);
  k_csr_scan<<<1, 1024, 0, stream>>>(deg, rowptr, cursor);
  k_scatter_encode<<<NE / 256, 256, 0, stream>>>(dst, src, cursor, src_s, dst_s,
                                                 d_d, We, be, flag, e);

  for (int l = 0; l < NL; l++) {
    if (l == 0)
      k_edge<true><<<NE / 128, 256, 0, stream>>>(feat, e, src_s, dst_s, Wt1, Wt2p,
                                                 mb1, mb2, sW, sb, flag, v0f, msum, l);
    else
      k_edge<false><<<NE / 128, 256, 0, stream>>>(feat, e, src_s, dst_s, Wt1, Wt2p,
                                                  mb1, mb2, sW, sb, flag, v0f, msum, l);
    if (l < NL - 1)
      k_node<false><<<NN / 32, 64, 0, stream>>>(feat, msum, Wtu1, Wtu2p, ub1, ub2,
                                                flag, l, seg, Wto1, Wto2p, ob1, ob2,
                                                sacc, mx, cnt);
    else
      k_node<true><<<NN / 32, 64, 0, stream>>>(feat, msum, Wtu1, Wtu2p, ub1, ub2,
                                               flag, l, seg, Wto1, Wto2p, ob1, ob2,
                                               sacc, mx, cnt);
  }
  k_final<<<(NB * 384) / 256, 256, 0, stream>>>(sacc, mx, cnt, flag, d_out);
}